// Round 11
// baseline (679.042 us; speedup 1.0000x reference)
//
#include <hip/hip_runtime.h>
#include <math.h>

#define DMODEL 256
#define PWAYS  4096
#define TOPK   4
#define HMAX   1280
#define NTOK   2048          // B*S
#define NPAIR  (NTOK*TOPK)   // 8192
#define FSLOTS 16
#define MROWS  64
#define YMLP   8
#define CTOT   56            // total mlp (expert,chunk) pairs: sum over e of 2+e/4

typedef __attribute__((ext_vector_type(8))) short bf16x8;
typedef __attribute__((ext_vector_type(8))) unsigned short u16x8;
typedef __attribute__((ext_vector_type(4))) float f32x4;

#define MFMA_BF16 __builtin_amdgcn_mfma_f32_16x16x32_bf16

__device__ __forceinline__ float gelu_exact(float z) {
    return 0.5f * z * (1.0f + erff(z * 0.70710678118654752440f));
}

__device__ __forceinline__ unsigned short f32_to_bf16_rne(float f) {
    unsigned u = __float_as_uint(f);
    unsigned r = u + 0x7FFFu + ((u >> 16) & 1u);
    return (unsigned short)(r >> 16);
}

__device__ __forceinline__ float bf16_to_f32(unsigned short h) {
    return __uint_as_float((unsigned)h << 16);
}

// chunk_base(e) = sum over e'<e of (2 + e'/4); total = 56
__device__ __forceinline__ int chunk_base(int e) {
    int g = e >> 2, r = e & 3;
    return 4 * (2 * g + (g * (g - 1)) / 2) + r * (2 + g);
}

// ============ front pack (1 launch: cvtx + pack12 + pack3 + packq + zero) ============
// blocks [0,512): x fp32 -> split-bf16
//        [512,536): rw1/rw2 pack
//        [536,792): rw3 pack
//        [792,1048): pw/qw pack
//        [1048]: zero counts/offsets/cursors (incl. topk ticket at counts[48])
__global__ void __launch_bounds__(256) k_pack_front(
    const float* __restrict__ x,
    const float* __restrict__ rw1, const float* __restrict__ rw2,
    const float* __restrict__ rw3,
    const float* __restrict__ pw, const float* __restrict__ qw,
    unsigned short* __restrict__ xth, unsigned short* __restrict__ xtl,
    unsigned short* __restrict__ R1P, unsigned short* __restrict__ R2P,
    unsigned short* __restrict__ P3,
    unsigned short* __restrict__ PPK, unsigned short* __restrict__ QPK,
    int* __restrict__ cnts) {
    const int wg = blockIdx.x;
    const int tid = threadIdx.x;
    const int lane = tid & 63;
    const int l15 = lane & 15, lhi = lane >> 4;

    if (wg < 512) {                       // ---- cvtx ----
        const size_t i = ((size_t)wg * 256 + tid) * 4;
        const float4 v = *(const float4*)&x[i];
        ushort4 hv, lv;
        hv.x = f32_to_bf16_rne(v.x); lv.x = f32_to_bf16_rne(v.x - bf16_to_f32(hv.x));
        hv.y = f32_to_bf16_rne(v.y); lv.y = f32_to_bf16_rne(v.y - bf16_to_f32(hv.y));
        hv.z = f32_to_bf16_rne(v.z); lv.z = f32_to_bf16_rne(v.z - bf16_to_f32(hv.z));
        hv.w = f32_to_bf16_rne(v.w); lv.w = f32_to_bf16_rne(v.w - bf16_to_f32(hv.w));
        *(ushort4*)&xth[i] = hv;
        *(ushort4*)&xtl[i] = lv;
    } else if (wg < 536) {                // ---- pack12 ----
        const int bx = wg - 512;
        const int kq = tid >> 6;
        const bool is1 = (bx < 16);
        const int nb = is1 ? bx : (bx - 16);
        const int N = is1 ? 256 : 128;
        const float* src = is1 ? rw1 : rw2;
        unsigned short* dst = is1 ? R1P : R2P;
        const int nblk = is1 ? 16 : 8;
        const int pstride = nblk * 8 * 512;
        const int n = nb * 16 + l15;
        for (int k2 = 0; k2 < 2; ++k2) {
            const int kb = kq + k2 * 4;
            const int k0 = kb * 32 + lhi * 8;
            u16x8 hv, lv;
#pragma unroll
            for (int j = 0; j < 8; ++j) {
                const float f = src[(size_t)(k0 + j) * N + n];
                const unsigned short h = f32_to_bf16_rne(f);
                hv[j] = h;
                lv[j] = f32_to_bf16_rne(f - bf16_to_f32(h));
            }
            const size_t o = ((size_t)nb * 8 + kb) * 512 + (size_t)lane * 8;
            *(u16x8*)&dst[o] = hv;
            *(u16x8*)&dst[o + pstride] = lv;
        }
    } else if (wg < 792) {                // ---- pack3 ----
        const int nb = wg - 536;
        const int kb = tid >> 6;
        const int k0 = kb * 32 + lhi * 8;
        const int n = nb * 16 + l15;
        u16x8 hv, lv;
#pragma unroll
        for (int j = 0; j < 8; ++j) {
            const float f = rw3[(size_t)(k0 + j) * PWAYS + n];
            const unsigned short h = f32_to_bf16_rne(f);
            hv[j] = h;
            lv[j] = f32_to_bf16_rne(f - bf16_to_f32(h));
        }
        const size_t o0 = ((size_t)(0 * 256 + nb) * 4 + kb) * 512 + (size_t)lane * 8;
        const size_t o1 = ((size_t)(1 * 256 + nb) * 4 + kb) * 512 + (size_t)lane * 8;
        *(u16x8*)&P3[o0] = hv;
        *(u16x8*)&P3[o1] = lv;
    } else if (wg < 1048) {               // ---- packq ----
        const int idx = wg - 792;
        const int e = idx & 15, which = (idx >> 4) & 1, kb = idx >> 5;
        const int wid = tid >> 6;
        const float* src = which ? qw : pw;
        unsigned short* dst = which ? QPK : PPK;
        for (int nb = wid; nb < 16; nb += 4) {
            const int n = nb * 16 + l15;
            const int k0 = kb * 32 + lhi * 8;
            u16x8 hv, lv;
#pragma unroll
            for (int j = 0; j < 8; ++j) {
                const float f = src[(size_t)e * DMODEL * DMODEL + (size_t)(k0 + j) * DMODEL + n];
                const unsigned short h = f32_to_bf16_rne(f);
                hv[j] = h;
                lv[j] = f32_to_bf16_rne(f - bf16_to_f32(h));
            }
            const size_t o0 = ((((size_t)e * 2 + 0) * 16 + nb) * 8 + kb) * 512 + (size_t)lane * 8;
            const size_t o1 = ((((size_t)e * 2 + 1) * 16 + nb) * 8 + kb) * 512 + (size_t)lane * 8;
            *(u16x8*)&dst[o0] = hv;
            *(u16x8*)&dst[o1] = lv;
        }
    } else {                              // ---- wg==1048: zero counts+offsets+cursors ----
        if (tid < 192) cnts[tid] = 0;
    }
}

// ---- mlp weight pack (runs AFTER k_freq: W1P/W2P overlap the scores overlay) ----
__global__ void __launch_bounds__(256) k_packw(
    const float* __restrict__ mw1, const float* __restrict__ mw2,
    unsigned short* __restrict__ W1P, unsigned short* __restrict__ W2P) {
    const int cl = blockIdx.x;          // 0..55
    const int which = blockIdx.y;       // 0: W1, 1: W2
    const int kb = blockIdx.z;          // 0..7
    int e = 0;
    while (e < 15 && chunk_base(e + 1) <= cl) ++e;
    const int ch = cl - chunk_base(e);
    const int hbase = ch * 256;
    const int tid = threadIdx.x;
    const int wid = tid >> 6, lane = tid & 63;
    const int l15 = lane & 15, lhi = lane >> 4;

    unsigned short* dst = which ? W2P : W1P;

    for (int nb = wid; nb < 16; nb += 4) {
        const int n = nb * 16 + l15;
        const int k0 = kb * 32 + lhi * 8;
        u16x8 hv, lv;
#pragma unroll
        for (int j = 0; j < 8; ++j) {
            float f;
            if (which == 0)
                f = mw1[((size_t)e * DMODEL + (k0 + j)) * HMAX + hbase + n];
            else
                f = mw2[((size_t)e * HMAX + hbase + k0 + j) * DMODEL + n];
            const unsigned short h = f32_to_bf16_rne(f);
            hv[j] = h;
            lv[j] = f32_to_bf16_rne(f - bf16_to_f32(h));
        }
        const size_t o0 = ((((size_t)cl * 2 + 0) * 16 + nb) * 8 + kb) * 512 + (size_t)lane * 8;
        const size_t o1 = ((((size_t)cl * 2 + 1) * 16 + nb) * 8 + kb) * 512 + (size_t)lane * 8;
        *(u16x8*)&dst[o0] = hv;
        *(u16x8*)&dst[o1] = lv;
    }
}

// ======================= shared front-end =======================

// zero out[] + x_mlp (both atomic-accumulated)
__global__ void k_zero2(float* __restrict__ out, float* __restrict__ x_mlp) {
    const int i = blockIdx.x * 256 + threadIdx.x;
    const int stride = gridDim.x * 256;
    for (int j = i; j < NTOK * DMODEL; j += stride) out[j] = 0.0f;
    for (int j = i; j < NPAIR * DMODEL; j += stride) x_mlp[j] = 0.0f;
}

// ---- fused router MLP: h1 = gelu(x@rw1+b1); h2 = gelu(h1@rw2+b2) (MFMA) ----
__global__ void __launch_bounds__(256, 2) k_h12(
    const unsigned short* __restrict__ xth, const unsigned short* __restrict__ xtl,
    const unsigned short* __restrict__ R1P, const unsigned short* __restrict__ R2P,
    const float* __restrict__ rb1, const float* __restrict__ rb2,
    unsigned short* __restrict__ h2h, unsigned short* __restrict__ h2l) {
    const int n0 = blockIdx.x * 32;
    const int tid = threadIdx.x;
    const int wid = tid >> 6, lane = tid & 63;
    const int l15 = lane & 15, lhi = lane >> 4;

    __shared__ unsigned short ah[32][264];
    __shared__ unsigned short al[32][264];

    for (int t = tid; t < 1024; t += 256) {
        const int row = t >> 5, seg = (t & 31) * 8;
        const size_t g = (size_t)(n0 + row) * DMODEL + seg;
        *(u16x8*)&ah[row][seg] = *(const u16x8*)&xth[g];
        *(u16x8*)&al[row][seg] = *(const u16x8*)&xtl[g];
    }
    __syncthreads();

    {
        f32x4 acc[2][4];
        const f32x4 zf = {0.f, 0.f, 0.f, 0.f};
#pragma unroll
        for (int ms = 0; ms < 2; ++ms)
#pragma unroll
            for (int ns = 0; ns < 4; ++ns) acc[ms][ns] = zf;

#pragma unroll 1
        for (int kb = 0; kb < 8; ++kb) {
            const int ko = kb * 32 + lhi * 8;
            const bf16x8 a_h0 = *(const bf16x8*)&ah[l15][ko];
            const bf16x8 a_h1 = *(const bf16x8*)&ah[16 + l15][ko];
            const bf16x8 a_l0 = *(const bf16x8*)&al[l15][ko];
            const bf16x8 a_l1 = *(const bf16x8*)&al[16 + l15][ko];
#pragma unroll
            for (int ns = 0; ns < 4; ++ns) {
                const size_t bo = ((size_t)(wid * 4 + ns) * 8 + kb) * 512 + (size_t)lane * 8;
                const bf16x8 bh = *(const bf16x8*)&R1P[bo];
                const bf16x8 bl = *(const bf16x8*)&R1P[bo + 65536];
                acc[0][ns] = MFMA_BF16(a_h0, bh, acc[0][ns], 0, 0, 0);
                acc[1][ns] = MFMA_BF16(a_h1, bh, acc[1][ns], 0, 0, 0);
                acc[0][ns] = MFMA_BF16(a_l0, bh, acc[0][ns], 0, 0, 0);
                acc[1][ns] = MFMA_BF16(a_l1, bh, acc[1][ns], 0, 0, 0);
                acc[0][ns] = MFMA_BF16(a_h0, bl, acc[0][ns], 0, 0, 0);
                acc[1][ns] = MFMA_BF16(a_h1, bl, acc[1][ns], 0, 0, 0);
            }
        }
        __syncthreads();

#pragma unroll
        for (int ms = 0; ms < 2; ++ms)
#pragma unroll
            for (int ns = 0; ns < 4; ++ns) {
                const int col = wid * 64 + ns * 16 + l15;
                const float bias = rb1[col];
#pragma unroll
                for (int r = 0; r < 4; ++r) {
                    const int row = ms * 16 + lhi * 4 + r;
                    const float v = gelu_exact(acc[ms][ns][r] + bias);
                    const unsigned short h = f32_to_bf16_rne(v);
                    ah[row][col] = h;
                    al[row][col] = f32_to_bf16_rne(v - bf16_to_f32(h));
                }
            }
        __syncthreads();
    }

    {
        f32x4 acc2[2][2];
        const f32x4 zf = {0.f, 0.f, 0.f, 0.f};
#pragma unroll
        for (int ms = 0; ms < 2; ++ms)
#pragma unroll
            for (int ns = 0; ns < 2; ++ns) acc2[ms][ns] = zf;

#pragma unroll 1
        for (int kb = 0; kb < 8; ++kb) {
            const int ko = kb * 32 + lhi * 8;
            const bf16x8 a_h0 = *(const bf16x8*)&ah[l15][ko];
            const bf16x8 a_h1 = *(const bf16x8*)&ah[16 + l15][ko];
            const bf16x8 a_l0 = *(const bf16x8*)&al[l15][ko];
            const bf16x8 a_l1 = *(const bf16x8*)&al[16 + l15][ko];
#pragma unroll
            for (int ns = 0; ns < 2; ++ns) {
                const int nb = wid * 2 + ns;
                const size_t bo = ((size_t)nb * 8 + kb) * 512 + (size_t)lane * 8;
                const bf16x8 bh = *(const bf16x8*)&R2P[bo];
                const bf16x8 bl = *(const bf16x8*)&R2P[bo + 32768];
                acc2[0][ns] = MFMA_BF16(a_h0, bh, acc2[0][ns], 0, 0, 0);
                acc2[1][ns] = MFMA_BF16(a_h1, bh, acc2[1][ns], 0, 0, 0);
                acc2[0][ns] = MFMA_BF16(a_l0, bh, acc2[0][ns], 0, 0, 0);
                acc2[1][ns] = MFMA_BF16(a_l1, bh, acc2[1][ns], 0, 0, 0);
                acc2[0][ns] = MFMA_BF16(a_h0, bl, acc2[0][ns], 0, 0, 0);
                acc2[1][ns] = MFMA_BF16(a_h1, bl, acc2[1][ns], 0, 0, 0);
            }
        }

#pragma unroll
        for (int ms = 0; ms < 2; ++ms)
#pragma unroll
            for (int ns = 0; ns < 2; ++ns) {
                const int col = wid * 32 + ns * 16 + l15;
                const float bias = rb2[col];
#pragma unroll
                for (int r = 0; r < 4; ++r) {
                    const int row = ms * 16 + lhi * 4 + r;
                    const float v = gelu_exact(acc2[ms][ns][r] + bias);
                    const unsigned short h = f32_to_bf16_rne(v);
                    const size_t o = (size_t)(n0 + row) * 128 + col;
                    h2h[o] = h;
                    h2l[o] = f32_to_bf16_rne(v - bf16_to_f32(h));
                }
            }
    }
}

// ---- scores GEMM: [2048,128] @ [128,4096] split-bf16 MFMA ----
// 1-D grid, wg&15 = col-tile: all 64 token-tiles of a col-tile share wg%8
// -> one XCD -> its 256KB P3 slice is L2-resident (R6 placement rule).
__global__ void __launch_bounds__(256, 2) k_scores(
    const unsigned short* __restrict__ h2h, const unsigned short* __restrict__ h2l,
    const unsigned short* __restrict__ P3, const float* __restrict__ rb3,
    float* __restrict__ scores) {
    const int wg = blockIdx.x;
    const int by = wg & 15;
    const int n0 = (wg >> 4) * 32;
    const int tid = threadIdx.x;
    const int wid = tid >> 6, lane = tid & 63;
    const int l15 = lane & 15, lhi = lane >> 4;

    __shared__ unsigned short ah[32][136];
    __shared__ unsigned short al[32][136];

    for (int t = tid; t < 512; t += 256) {
        const int row = t >> 4, seg = (t & 15) * 8;
        const size_t g = (size_t)(n0 + row) * 128 + seg;
        *(u16x8*)&ah[row][seg] = *(const u16x8*)&h2h[g];
        *(u16x8*)&al[row][seg] = *(const u16x8*)&h2l[g];
    }
    __syncthreads();

    f32x4 acc[2][4];
    const f32x4 zf = {0.f, 0.f, 0.f, 0.f};
#pragma unroll
    for (int ms = 0; ms < 2; ++ms)
#pragma unroll
        for (int ns = 0; ns < 4; ++ns) acc[ms][ns] = zf;

#pragma unroll 1
    for (int kb = 0; kb < 4; ++kb) {
        const int ko = kb * 32 + lhi * 8;
        const bf16x8 a_h0 = *(const bf16x8*)&ah[l15][ko];
        const bf16x8 a_h1 = *(const bf16x8*)&ah[16 + l15][ko];
        const bf16x8 a_l0 = *(const bf16x8*)&al[l15][ko];
        const bf16x8 a_l1 = *(const bf16x8*)&al[16 + l15][ko];
#pragma unroll
        for (int ns = 0; ns < 4; ++ns) {
            const int nb = by * 16 + wid * 4 + ns;
            const size_t bo = ((size_t)nb * 4 + kb) * 512 + (size_t)lane * 8;
            const bf16x8 bh = *(const bf16x8*)&P3[bo];
            const bf16x8 bl = *(const bf16x8*)&P3[bo + 524288];
            acc[0][ns] = MFMA_BF16(a_h0, bh, acc[0][ns], 0, 0, 0);
            acc[1][ns] = MFMA_BF16(a_h1, bh, acc[1][ns], 0, 0, 0);
            acc[0][ns] = MFMA_BF16(a_l0, bh, acc[0][ns], 0, 0, 0);
            acc[1][ns] = MFMA_BF16(a_l1, bh, acc[1][ns], 0, 0, 0);
            acc[0][ns] = MFMA_BF16(a_h0, bl, acc[0][ns], 0, 0, 0);
            acc[1][ns] = MFMA_BF16(a_h1, bl, acc[1][ns], 0, 0, 0);
        }
    }

#pragma unroll
    for (int ms = 0; ms < 2; ++ms)
#pragma unroll
        for (int ns = 0; ns < 4; ++ns) {
            const int col = by * 256 + wid * 64 + ns * 16 + l15;
            const float bias = rb3[col];
#pragma unroll
            for (int r = 0; r < 4; ++r) {
                const int row = n0 + ms * 16 + lhi * 4 + r;
                scores[(size_t)row * PWAYS + col] = acc[ms][ns][r] + bias;
            }
        }
}

// ---- per-token softmax stats + top-4; full pw_out row; counts atomics;
//      last block (device ticket) computes prefix via all-atomic reads ----
__global__ void __launch_bounds__(256) k_topk(
    const float* __restrict__ scores, const float* __restrict__ temp,
    int* __restrict__ top_idx, float* __restrict__ top_vals,
    float* __restrict__ pw_out, float* __restrict__ tok_m, float* __restrict__ tok_i,
    int* __restrict__ counts, int* __restrict__ offsets, int* __restrict__ cursors) {
    const int n = blockIdx.x;
    const int tid = threadIdx.x;
    const int wid = tid >> 6, lane = tid & 63;
    const float* row = scores + (size_t)n * PWAYS;

    float sv[16];
#pragma unroll
    for (int i = 0; i < 16; ++i) sv[i] = row[tid + i * 256];

    __shared__ float wred[4];
    __shared__ float wr1[4], wrT[4];
    __shared__ float wbv[4];
    __shared__ int wbi[4];
    __shared__ int sel[TOPK];
    __shared__ float selv[TOPK];
    __shared__ float pwv[TOPK];
    __shared__ int lastflag;
    __shared__ int cshared[48];

    float lmax = -3.402823466e38f;
#pragma unroll
    for (int i = 0; i < 16; ++i) lmax = fmaxf(lmax, sv[i]);
    for (int o = 32; o > 0; o >>= 1) lmax = fmaxf(lmax, __shfl_down(lmax, o));
    if (lane == 0) wred[wid] = lmax;
    __syncthreads();
    const float m = fmaxf(fmaxf(wred[0], wred[1]), fmaxf(wred[2], wred[3]));

    const float invT = 1.0f / temp[0];
    float e1 = 0.f, eT = 0.f;
#pragma unroll
    for (int i = 0; i < 16; ++i) {
        const float d = sv[i] - m;
        e1 += expf(d);
        eT += expf(d * invT);
    }
    for (int o = 32; o > 0; o >>= 1) { e1 += __shfl_down(e1, o); eT += __shfl_down(eT, o); }
    if (lane == 0) { wr1[wid] = e1; wrT[wid] = eT; }
    __syncthreads();
    const float sum1 = wr1[0] + wr1[1] + wr1[2] + wr1[3];
    const float sumT = wrT[0] + wrT[1] + wrT[2] + wrT[3];

    for (int r = 0; r < TOPK; ++r) {
        float bv = -3.402823466e38f;
        int bi = PWAYS;
#pragma unroll
        for (int i = 0; i < 16; ++i) {
            const int p = tid + i * 256;
            bool skip = false;
            for (int u = 0; u < r; ++u) if (sel[u] == p) skip = true;
            if (!skip && sv[i] > bv) { bv = sv[i]; bi = p; }
        }
        for (int o = 32; o > 0; o >>= 1) {
            const float ov = __shfl_down(bv, o);
            const int oi = __shfl_down(bi, o);
            if (ov > bv || (ov == bv && oi < bi)) { bv = ov; bi = oi; }
        }
        if (lane == 0) { wbv[wid] = bv; wbi[wid] = bi; }
        __syncthreads();
        if (tid == 0) {
            float b = wbv[0]; int bidx = wbi[0];
            for (int w = 1; w < 4; ++w)
                if (wbv[w] > b || (wbv[w] == b && wbi[w] < bidx)) { b = wbv[w]; bidx = wbi[w]; }
            sel[r] = bidx; selv[r] = b;
        }
        __syncthreads();
    }

    if (tid == 0) {
        float tv[TOPK];
        float wsum = 1e-8f;
#pragma unroll
        for (int k2 = 0; k2 < TOPK; ++k2) {
            tv[k2] = expf((selv[k2] - m) * invT) / sumT;
            wsum += tv[k2];
        }
        const float invw = 1.0f / wsum;
#pragma unroll
        for (int k2 = 0; k2 < TOPK; ++k2) {
            top_idx[n * TOPK + k2] = sel[k2];
            top_vals[n * TOPK + k2] = tv[k2];
            pwv[k2] = tv[k2] * invw;
        }
        tok_m[n] = m;
        tok_i[n] = 1.0f / sum1;
        // per-stage routing counts (was k_count)
#pragma unroll
        for (int r = 0; r < TOPK; ++r) {
            const int idx = sel[r];
            atomicAdd(&counts[0 * 16 + (idx >> 8)], 1);
            atomicAdd(&counts[1 * 16 + ((idx >> 4) & 15)], 1);
            atomicAdd(&counts[2 * 16 + (idx & 15)], 1);
        }
    }
    __syncthreads();

    // full-row write of pathway weights (no pre-zero needed)
#pragma unroll
    for (int i = 0; i < 16; ++i) {
        const int p = tid + i * 256;
        float v = 0.0f;
#pragma unroll
        for (int r = 0; r < TOPK; ++r) if (p == sel[r]) v = pwv[r];
        pw_out[(size_t)n * PWAYS + p] = v;
    }

    // completion ticket (counts[48]); last block computes prefix (was k_prefix).
    // threadfence orders this block's count-atomics before its ticket bump.
    if (tid == 0) {
        __threadfence();
        lastflag = (atomicAdd(&counts[48], 1) == NTOK - 1);
    }
    __syncthreads();
    if (lastflag) {
        if (tid < 48) cshared[tid] = atomicAdd(&counts[tid], 0);  // coherent read
        __syncthreads();
        if (tid == 0) {
            for (int s = 0; s < 3; ++s) {
                int run = 0;
                for (int e2 = 0; e2 < 16; ++e2) {
                    offsets[s * 16 + e2] = run;
                    cursors[s * 16 + e2] = run;
                    run += cshared[s * 16 + e2];
                }
            }
        }
    }
}

// ---- freq: exclusive-write partial sums of softmax probs (no atomics) ----
__global__ void __launch_bounds__(256) k_freq(
    const float* __restrict__ scores, const float* __restrict__ tok_m,
    const float* __restrict__ tok_i, float* __restrict__ freq_part) {
    const int bx = blockIdx.x;
    const int by = blockIdx.y;
    const int tid = threadIdx.x;
    const int wid = tid >> 6, lane = tid & 63;
    const int col = bx * 64 + lane;

    float acc = 0.f;
    const int r0 = by * 128;
    for (int r = r0 + wid; r < r0 + 128; r += 4) {
        const float mm = tok_m[r], iv = tok_i[r];
        acc += expf(scores[(size_t)r * PWAYS + col] - mm) * iv;
    }
    __shared__ float fs[4][64];
    fs[wid][lane] = acc;
    __syncthreads();
    if (wid == 0)
        freq_part[(size_t)by * PWAYS + col] = fs[0][lane] + fs[1][lane] + fs[2][lane] + fs[3][lane];
}

__global__ void k_freq_loss(const float* __restrict__ freq_part, float* __restrict__ out_loss) {
    __shared__ float fl[PWAYS];
    __shared__ float red[256];
    const int tid = threadIdx.x;
    for (int p = tid; p < PWAYS; p += 256) {
        float s = 0.f;
        for (int sl = 0; sl < FSLOTS; sl++) s += freq_part[(size_t)sl * PWAYS + p];
        fl[p] = s * (1.0f / NTOK);
    }
    __syncthreads();
    float s = 0.f;
    for (int p = tid; p < PWAYS; p += 256) s += fl[p];
    red[tid] = s; __syncthreads();
    for (int st = 128; st > 0; st >>= 1) { if (tid < st) red[tid] += red[tid + st]; __syncthreads(); }
    const float mu = red[0] * (1.0f / PWAYS);
    __syncthreads();
    float ss = 0.f;
    for (int p = tid; p < PWAYS; p += 256) {
        float d = fl[p] - mu;
        ss += d * d;
    }
    red[tid] = ss; __syncthreads();
    for (int st = 128; st > 0; st >>= 1) { if (tid < st) red[tid] += red[tid + st]; __syncthreads(); }
    if (tid == 0)
        out_loss[0] = (float)PWAYS * red[0] / (float)(PWAYS - 1);
}

// ======================= expert-batched back-end =======================

__global__ void k_scatter(const int* __restrict__ top_idx, int* __restrict__ cursors,
                          int* __restrict__ lists) {
    const int p = blockIdx.x * 256 + threadIdx.x;
    if (p >= NPAIR) return;
    const int idx = top_idx[p];
    int pos;
    pos = atomicAdd(&cursors[0 * 16 + (idx >> 8)], 1);        lists[0 * NPAIR + pos] = p;
    pos = atomicAdd(&cursors[1 * 16 + ((idx >> 4) & 15)], 1); lists[1 * NPAIR + pos] = p;
    pos = atomicAdd(&cursors[2 * 16 + (idx & 15)], 1);        lists[2 * NPAIR + pos] = p;
}

// ---- stage A: pre experts — MFMA Linear + in-fragment LN + act -> split-bf16 ----
__global__ void __launch_bounds__(256, 2) k_pre_mfma(
    const unsigned short* __restrict__ xth, const unsigned short* __restrict__ xtl,
    const unsigned short* __restrict__ PPK,
    const float* __restrict__ pb, const float* __restrict__ pg, const float* __restrict__ pbb,
    const int* __restrict__ counts, const int* __restrict__ offsets,
    const int* __restrict__ lists,
    unsigned short* __restrict__ x_h, unsigned short* __restrict__ x_l) {
    const int e = blockIdx.x;
    const int cnt = counts[e];
    if (cnt == 0) return;
    const int off = offsets[e];
    const int am = e % 3;
    const int tid = threadIdx.x;
    const int wid = tid >> 6, lane = tid & 63;
    const int l15 = lane & 15, lhi = lane >> 4;

    __shared__ int prs[32];
    __shared__ unsigned short ah[32][264];
    __shared__ unsigned short al[32][264];
    __shared__ float s1s[4][32], s2s[4][32];
    __shared__ float mus[32], ivs[32];

    float bias4[4], g4[4], bb4[4];
#pragma unroll
    for (int ns = 0; ns < 4; ++ns) {
        const int col = wid * 64 + ns * 16 + l15;
        bias4[ns] = pb[e * DMODEL + col];
        g4[ns] = pg[e * DMODEL + col];
        bb4[ns] = pbb[e * DMODEL + col];
    }
    const size_t wbase = (size_t)e * 2 * 65536;

    for (int base = blockIdx.y * 32; base < cnt; base += 16 * 32) {
        const int Tact = min(32, cnt - base);
        if (tid < 32) prs[tid] = lists[off + base + min(tid, Tact - 1)];
        __syncthreads();
        for (int t = tid; t < 1024; t += 256) {
            const int row = t >> 5, seg = (t & 31) * 8;
            const size_t gsrc = (size_t)(prs[row] >> 2) * DMODEL + seg;
            *(uint4*)&ah[row][seg] = *(const uint4*)&xth[gsrc];
            *(uint4*)&al[row][seg] = *(const uint4*)&xtl[gsrc];
        }
        __syncthreads();

        f32x4 acc[2][4];
        const f32x4 zf = {0.f, 0.f, 0.f, 0.f};
#pragma unroll
        for (int ms = 0; ms < 2; ++ms)
#pragma unroll
            for (int ns = 0; ns < 4; ++ns) acc[ms][ns] = zf;

#pragma unroll 1
        for (int kb = 0; kb < 8; ++kb) {
            const int ko = kb * 32 + lhi * 8;
            const bf16x8 a_h0 = *(const bf16x8*)&ah[l15][ko];
            const bf16x8 a_h1 = *(const bf16x8*)&ah[16 + l15][ko];
            const bf16x8 a_l0 = *(const bf16x8*)&al[l15][ko];
            const bf16x8 a_l1 = *(const bf16x8*)&al[16 + l15][ko];
#pragma unroll
            for (int ns = 0; ns < 4; ++ns) {
                const size_t bo = wbase + (size_t)(((wid * 4 + ns) * 8 + kb) * 512 + lane * 8);
                const bf16x8 bh = *(const bf16x8*)&PPK[bo];
                const bf16x8 bl = *(const bf16x8*)&PPK[bo + 65536];
                acc[0][ns] = MFMA_BF16(a_h0, bh, acc[0][ns], 0, 0, 0);
                acc[1][ns] = MFMA_BF16(a_h1, bh, acc[1][ns], 0, 0, 0);
                acc[0][ns] = MFMA_BF16(a_l0, bh, acc[0][ns], 0, 0, 0);
                acc[1][ns] = MFMA_BF16(a_l1, bh, acc[1][ns], 0, 0, 0);
                acc[0][ns] = MFMA_BF16(a_h0, bl, acc[0][ns], 0, 0, 0);
                acc[1][ns] = MFMA_BF16(a_h1, bl, acc[1][ns], 0, 0, 0);
            }
        }

#pragma unroll
        for (int ms = 0; ms < 2; ++ms)
#pragma unroll
            for (int r = 0; r < 4; ++r) {
                float s1 = 0.f, s2 = 0.f;
#pragma unroll
                for (int ns = 0; ns < 4; ++ns) {
                    const float v = acc[ms][ns][r] + bias4[ns];
                    s1 += v; s2 += v * v;
                }
#pragma unroll
                for (int o = 1; o < 16; o <<= 1) {
                    s1 += __shfl_xor(s1, o);
                    s2 += __shfl_xor(s2, o);
                }
                if (l15 == 0) {
                    s1s[wid][ms * 16 + lhi * 4 + r] = s1;
                    s2s[wid][ms * 16 + lhi * 4 + r] = s2;
                }
            }
        __syncthreads();
        if (tid < 32) {
            const float s1 = s1s[0][tid] + s1s[1][tid] + s1s[2][tid] + s1s[3][tid];
            const float s2 = s2s[0][tid] + s2s[1][tid] + s2s[2][tid] + s2s[3][tid];
            const float mu = s1 * (1.0f / DMODEL);
            mus[tid] = mu;
            ivs[tid] = rsqrtf(s2 * (1.0f / DMODEL) - mu * mu + 1e-5f);
        }
        __syncthreads();

#pragma unroll
        for (int ms = 0; ms < 2; ++ms)
#pragma unroll
            for (int ns = 0; ns < 4; ++ns) {
                const int col = wid * 64 + ns * 16 + l15;
#pragma unroll
                for (int r = 0; r < 4; ++r) {
                    const int row = ms * 16 + lhi * 4 + r;
                    if (row < Tact) {
                        const float v = acc[ms][ns][r] + bias4[ns];
                        float y = (v - mus[row]) * ivs[row] * g4[ns] + bb4[ns];
                        y = (am == 0) ? gelu_exact(y) : (am == 1 ? fmaxf(y, 0.f) : tanhf(y));
                        const unsigned short h = f32_to_bf16_rne(y);
                        const size_t o = (size_t)prs[row] * DMODEL + col;
                        x_h[o] = h;
                        x_l[o] = f32_to_bf16_rne(y - bf16_to_f32(h));
                    }
                }
            }
        __syncthreads();
    }
}

// ---- stage B: mlp experts — split-bf16 MFMA, 64-pair x 256-col tiles ----
// 1-D XCD-pinned grid (unchanged; control kernel).
__global__ void __launch_bounds__(256, 2) k_mlp_mfma(
    const unsigned short* __restrict__ x_h, const unsigned short* __restrict__ x_l,
    const unsigned short* __restrict__ W1P, const unsigned short* __restrict__ W2P,
    const float* __restrict__ mb1, const float* __restrict__ mb2,
    const int* __restrict__ counts, const int* __restrict__ offsets,
    const int* __restrict__ lists, float* __restrict__ x_mlp) {
    const int p = blockIdx.x & 7;
    const int j = blockIdx.x >> 3;       // 0..55
    const int ea = p;
    const int eb = (p < 4) ? (p + 12) : (p + 4);
    const int na = (2 + (ea >> 2)) * YMLP;
    int e, ch, y;
    if (j < na) { e = ea; ch = j >> 3; y = j & 7; }
    else        { e = eb; ch = (j - na) >> 3; y = (j - na) & 7; }

    const int cnt = counts[16 + e];
    if (cnt == 0) return;
    const int off = offsets[16 + e];
    const int cl = chunk_base(e) + ch;
    const bool is_gelu = ((e & 1) == 0);
    const int tid = threadIdx.x;
    const int wid = tid >> 6, lane = tid & 63;
    const int l15 = lane & 15, lhi = lane >> 4;

    __shared__ int prs[MROWS];
    __shared__ unsigned short ah[MROWS][264];
    __shared__ unsigned short al[MROWS][264];

    float hb_s[4], ob_s[4];
#pragma unroll
    for (int ns = 0; ns < 4; ++ns) {
        const int col = wid * 64 + ns * 16 + l15;
        hb_s[ns] = mb1[e * HMAX + ch * DMODEL + col];
        ob_s[ns] = (ch == 0) ? mb2[e * DMODEL + col] : 0.0f;
    }

    const size_t wbase = (size_t)cl * 2 * 65536;

    for (int base = y * MROWS; base < cnt; base += YMLP * MROWS) {
        const int Tact = min(MROWS, cnt - base);
        if (tid < MROWS) prs[tid] = lists[NPAIR + off + base + min(tid, Tact - 1)];
        __syncthreads();
        for (int t = tid; t < 2048; t += 256) {
            const int row = t >> 5, seg = (t & 31) * 8;
            const size_t gsrc = (size_t)prs[row] * DMODEL + seg;
            *(uint4*)&ah[row][seg] = *(const uint4*)&x_h[gsrc];
            *(uint4*)&al[row][seg] = *(const uint4*)&x_l[gsrc];
        }
        __syncthreads();

        {
            f32x4 acc[4][4];
            const f32x4 zf = {0.f, 0.f, 0.f, 0.f};
#pragma unroll
            for (int ms = 0; ms < 4; ++ms)
#pragma unroll
                for (int ns = 0; ns < 4; ++ns) acc[ms][ns] = zf;

#pragma unroll 1
            for (int kb = 0; kb < 8; ++kb) {
                const int ko = kb * 32 + lhi * 8;
#pragma unroll
                for (int ns = 0; ns < 4; ++ns) {
                    const size_t bo = wbase + (size_t)(((wid * 4 + ns) * 8 + kb) * 512 + lane * 8);
                    const bf16x8 bh = *(const bf16x8*)&W1P[bo];
                    const bf16x8 bl = *(const bf16x8*)&W1P[bo + 65536];
#pragma unroll
                    for (int ms = 0; ms < 4; ++ms) {
                        const bf16x8 a_h = *(const bf16x8*)&ah[ms * 16 + l15][ko];
                        const bf16x8 a_l = *(const bf16x8*)&al[ms * 16 + l15][ko];
                        acc[ms][ns] = MFMA_BF16(a_h, bh, acc[ms][ns], 0, 0, 0);
                        acc[ms][ns] = MFMA_BF16(a_l, bh, acc[ms][ns], 0, 0, 0);
                        acc[ms][ns] = MFMA_BF16(a_h, bl, acc[ms][ns], 0, 0, 0);
                    }
                }
            }
            __syncthreads();

#pragma unroll
            for (int ms = 0; ms < 4; ++ms)
#pragma unroll
                for (int ns = 0; ns < 4; ++ns) {
                    const int col = wid * 64 + ns * 16 + l15;
#pragma unroll
                    for (int r = 0; r < 4; ++r) {
                        const int row = ms * 16 + lhi * 4 + r;
                        float v = acc[ms][ns][r] + hb_s[ns];
                        v = is_gelu ? gelu_exact(v) : fmaxf(v, 0.0f);
                        const unsigned short h = f32_to_bf16_rne(v);
                        ah[row][col] = h;
                        al[row][col] = f32_to_bf16_rne(v - bf16_to_f32(h));
                    }
                }
            __syncthreads();
        }

        {
            f32x4 acc2[4][4];
            const f32x4 zf = {0.f, 0.f, 0.f, 0.f};
#pragma unroll
            for (int ms = 0; ms < 4; ++ms)
#pragma unroll
                for (int ns = 0; ns < 4; ++ns) acc2[ms][ns] = zf;

#pragma unroll 1
            for (int kb = 0; kb < 8; ++kb) {
                const int ko = kb * 32 + lhi * 8;
#pragma unroll
                for (int ns = 0; ns < 4; ++ns) {
                    const size_t bo = wbase + (size_t)(((wid * 4 + ns) * 8 + kb) * 512 + lane * 8);
                    const bf16x8 bh = *(const bf16x8*)&W2P[bo];
                    const bf16x8 bl = *(const bf16x8*)&W2P[bo + 65536];
#pragma unroll
                    for (int ms = 0; ms < 4; ++ms) {
                        const bf16x8 a_h = *(const bf16x8*)&ah[ms * 16 + l15][ko];
                        const bf16x8 a_l = *(const bf16x8*)&al[ms * 16 + l15][ko];
                        acc2[ms][ns] = MFMA_BF16(a_h, bh, acc2[ms][ns], 0, 0, 0);
                        acc2[ms][ns] = MFMA_BF16(a_l, bh, acc2[ms][ns], 0, 0, 0);
                        acc2[ms][ns] = MFMA_BF16(a_h, bl, acc2[ms][ns], 0, 0, 0);
                    }
                }
            }

#pragma unroll
            for (int ms = 0; ms < 4; ++ms)
#pragma unroll
                for (int ns = 0; ns < 4; ++ns) {
                    const int col = wid * 64 + ns * 16 + l15;
#pragma unroll
                    for (int r = 0; r < 4; ++r) {
                        const int row = ms * 16 + lhi * 4 + r;
                        if (row < Tact)
                            atomicAdd(&x_mlp[(size_t)prs[row] * DMODEL + col],
                                      acc2[ms][ns][r] + ob_s[ns]);
                    }
                }
        }
        __syncthreads();
    }
}

// ---- stage C: post experts — MFMA Linear (+LN if even) + weighted scatter ----
__global__ void __launch_bounds__(256, 2) k_post_mfma(
    const float* __restrict__ x_mlp,
    const unsigned short* __restrict__ QPK,
    const float* __restrict__ qb, const float* __restrict__ qg, const float* __restrict__ qbb,
    const float* __restrict__ top_val,
    const int* __restrict__ counts, const int* __restrict__ offsets,
    const int* __restrict__ lists, float* __restrict__ out) {
    const int e = blockIdx.x;
    const int cnt = counts[32 + e];
    if (cnt == 0) return;
    const int off = offsets[32 + e];
    const bool has_ln = ((e & 1) == 0);
    const int tid = threadIdx.x;
    const int wid = tid >> 6, lane = tid & 63;
    const int l15 = lane & 15, lhi = lane >> 4;

    __shared__ int prs[32];
    __shared__ float tvs[32];
    __shared__ unsigned short ah[32][264];
    __shared__ unsigned short al[32][264];
    __shared__ float s1s[4][32], s2s[4][32];
    __shared__ float mus[32], ivs[32];

    float bias4[4], g4[4], bb4[4];
#pragma unroll
    for (int ns = 0; ns < 4; ++ns) {
        const int col = wid * 64 + ns * 16 + l15;
        bias4[ns] = qb[e * DMODEL + col];
        g4[ns] = qg[e * DMODEL + col];
        bb4[ns] = qbb[e * DMODEL + col];
    }
    const size_t wbase = (size_t)e * 2 * 65536;

    for (int base = blockIdx.y * 32; base < cnt; base += 16 * 32) {
        const int Tact = min(32, cnt - base);
        if (tid < 32) {
            const int p = lists[2 * NPAIR + off + base + min(tid, Tact - 1)];
            prs[tid] = p;
            tvs[tid] = top_val[p];
        }
        __syncthreads();
        for (int t = tid; t < 1024; t += 256) {
            const int row = t >> 5, seg = (t & 31) * 8;
            const float* src = &x_mlp[(size_t)prs[row] * DMODEL + seg];
            const float4 v0 = *(const float4*)&src[0];
            const float4 v1 = *(const float4*)&src[4];
            u16x8 hv, lv;
            const float fv[8] = {v0.x, v0.y, v0.z, v0.w, v1.x, v1.y, v1.z, v1.w};
#pragma unroll
            for (int jj = 0; jj < 8; ++jj) {
                const unsigned short h = f32_to_bf16_rne(fv[jj]);
                hv[jj] = h;
                lv[jj] = f32_to_bf16_rne(fv[jj] - bf16_to_f32(h));
            }
            *(u16x8*)&ah[row][seg] = hv;
            *(u16x8*)&al[row][seg] = lv;
        }
        __syncthreads();

        f32x4 acc[2][4];
        const f32x4 zf = {0.f, 0.f, 0.f, 0.f};
#pragma unroll
        for (int ms = 0; ms < 2; ++ms)
#pragma unroll
            for (int ns = 0; ns < 4; ++ns) acc[ms][ns] = zf;

#pragma unroll 1
        for (int kb = 0; kb < 8; ++kb) {
            const int ko = kb * 32 + lhi * 8;
            const bf16x8 a_h0 = *(const bf16x8*)&ah[l15][ko];
            const bf16x8 a_h1 = *(const bf16x8*)&ah[16 + l15][ko];
            const bf16x8 a_l0 = *(const bf16x8*)&al[l15][ko];
            const bf16x8 a_l1 = *(const bf16x8*)&al[16 + l15][ko];
#pragma unroll
            for (int ns = 0; ns < 4; ++ns) {
                const size_t bo = wbase + (size_t)(((wid * 4 + ns) * 8 + kb) * 512 + lane * 8);
                const bf16x8 bh = *(const bf16x8*)&QPK[bo];
                const bf16x8 bl = *(const bf16x8*)&QPK[bo + 65536];
                acc[0][ns] = MFMA_BF16(a_h0, bh, acc[0][ns], 0, 0, 0);
                acc[1][ns] = MFMA_BF16(a_h1, bh, acc[1][ns], 0, 0, 0);
                acc[0][ns] = MFMA_BF16(a_l0, bh, acc[0][ns], 0, 0, 0);
                acc[1][ns] = MFMA_BF16(a_l1, bh, acc[1][ns], 0, 0, 0);
                acc[0][ns] = MFMA_BF16(a_h0, bl, acc[0][ns], 0, 0, 0);
                acc[1][ns] = MFMA_BF16(a_h1, bl, acc[1][ns], 0, 0, 0);
            }
        }

        if (has_ln) {
#pragma unroll
            for (int ms = 0; ms < 2; ++ms)
#pragma unroll
                for (int r = 0; r < 4; ++r) {
                    float s1 = 0.f, s2 = 0.f;
#pragma unroll
                    for (int ns = 0; ns < 4; ++ns) {
                        const float v = acc[ms][ns][r] + bias4[ns];
                        s1 += v; s2 += v * v;
                    }
#pragma unroll
                    for (int o = 1; o < 16; o <<= 1) {
                        s1 += __shfl_xor(s1, o);
                        s2 += __shfl_xor(s2, o);
                    }
                    if (l15 == 0) {
                        s1s[wid][ms * 16 + lhi * 4 + r] = s1;
                        s2s[wid][ms * 16 + lhi * 4 + r] = s2;
                    }
                }
            __syncthreads();
            if (tid < 32) {
                const float s1 = s1s[0][tid] + s1s[1][tid] + s1s[2][tid] + s1s[3][tid];
                const float s2 = s2s[0][tid] + s2s[1][tid] + s2s[2][tid] + s2s[3][tid];
                const float mu = s1 * (1.0f / DMODEL);
                mus[tid] = mu;
                ivs[tid] = rsqrtf(s2 * (1.0f / DMODEL) - mu * mu + 1e-5f);
            }
            __syncthreads();
        }

#pragma unroll
        for (int ms = 0; ms < 2; ++ms)
#pragma unroll
            for (int ns = 0; ns < 4; ++ns) {
                const int col = wid * 64 + ns * 16 + l15;
#pragma unroll
                for (int r = 0; r < 4; ++r) {
                    const int row = ms * 16 + lhi * 4 + r;
                    if (row < Tact) {
                        const float v = acc[ms][ns][r] + bias4[ns];
                        const float t = has_ln ? ((v - mus[row]) * ivs[row] * g4[ns] + bb4[ns]) : v;
                        atomicAdd(&out[(size_t)(prs[row] >> 2) * DMODEL + col], tvs[row] * t);
                    }
                }
            }
        __syncthreads();
    }
}

// ---------------------------------------------------------------------------
extern "C" void kernel_launch(void* const* d_in, const int* in_sizes, int n_in,
                              void* d_out, int out_size, void* d_ws, size_t ws_size,
                              hipStream_t stream) {
    (void)in_sizes; (void)n_in; (void)out_size; (void)ws_size;

    const float* x    = (const float*)d_in[0];
    const float* rw1  = (const float*)d_in[1];
    const float* rb1  = (const float*)d_in[2];
    const float* rw2  = (const float*)d_in[3];
    const float* rb2  = (const float*)d_in[4];
    const float* rw3  = (const float*)d_in[5];
    const float* rb3  = (const float*)d_in[6];
    const float* temp = (const float*)d_in[7];
    const float* pw   = (const float*)d_in[8];
    const float* pb   = (const float*)d_in[9];
    const float* pg   = (const float*)d_in[10];
    const float* pbb  = (const float*)d_in[11];
    const float* mw1  = (const float*)d_in[12];
    const float* mb1  = (const float*)d_in[13];
    const float* mw2  = (const float*)d_in[14];
    const float* mb2  = (const float*)d_in[15];
    const float* qw   = (const float*)d_in[16];
    const float* qb   = (const float*)d_in[17];
    const float* qg   = (const float*)d_in[18];
    const float* qbb  = (const float*)d_in[19];

    float* out      = (float*)d_out;
    float* out_loss = out + (size_t)NTOK * DMODEL;
    float* out_pw   = out_loss + 1;

    float* freq_part = (float*)d_ws;                                  // 65536 f
    int*   top_idx   = (int*)(freq_part + (size_t)FSLOTS * PWAYS);    // 8192 i
    float* top_val   = (float*)(top_idx + NPAIR);                     // 8192 f
    int*   counts    = (int*)(top_val + NPAIR);                       // 64 i ([48]=ticket)
    int*   offsets   = counts + 64;                                   // 64 i
    int*   cursors   = offsets + 64;                                  // 64 i
    int*   lists     = cursors + 64;                                  // 3*8192 i
    float* x_mlp     = (float*)(lists + 3 * NPAIR);                   // 8192*256 f
    unsigned short* x_h = (unsigned short*)(x_mlp + (size_t)NPAIR * DMODEL); // 8192*256 bf16
    unsigned short* x_l = x_h + (size_t)NPAIR * DMODEL;                      // 8192*256 bf16
    unsigned short* W1P = x_l + (size_t)NPAIR * DMODEL;               // 56*2*65536 bf16
    unsigned short* W2P = W1P + (size_t)CTOT * 2 * 65536;             // 56*2*65536 bf16
    unsigned short* P3  = W2P + (size_t)CTOT * 2 * 65536;             // 2*524288 bf16
    unsigned short* h2h = P3 + 2 * 524288;                            // 2048*128 bf16
    unsigned short* h2l = h2h + (size_t)NTOK * 128;                   // 2048*128 bf16
    float* tok_m = (float*)(h2l + (size_t)NTOK * 128);                // 2048 f
    float* tok_i = tok_m + NTOK;                                      // 2048 f
    unsigned short* xth = (unsigned short*)(tok_i + NTOK);            // 2048*256 bf16
    unsigned short* xtl = xth + (size_t)NTOK * DMODEL;                // 2048*256 bf16
    unsigned short* PPK = xtl + (size_t)NTOK * DMODEL;                // 16*2*65536 bf16
    unsigned short* QPK = PPK + (size_t)16 * 2 * 65536;               // 16*2*65536 bf16
    unsigned short* R1P = QPK + (size_t)16 * 2 * 65536;               // 2*65536 bf16
    unsigned short* R2P = R1P + 2 * 65536;                            // 2*32768 bf16
    // scores [2048][4096] f32 (33.5MB) overlays x_mlp..W2P. W1P/W2P overlap
    // the overlay, so the mlp weights are packed by k_packw AFTER k_freq
    // (when scores is dead). P3/PPK/QPK/R1P/R2P live outside the overlay.
    float* scores = x_mlp;

    // front pack: cvtx(512) + pack12(24) + pack3(256) + packq(256) + zero(1)
    k_pack_front<<<1049, 256, 0, stream>>>(x, rw1, rw2, rw3, pw, qw,
                                           xth, xtl, R1P, R2P, P3, PPK, QPK,
                                           counts);
    k_h12<<<NTOK / 32, 256, 0, stream>>>(xth, xtl, R1P, R2P, rb1, rb2, h2h, h2l);
    k_scores<<<1024, 256, 0, stream>>>(h2h, h2l, P3, rb3, scores);
    k_topk<<<NTOK, 256, 0, stream>>>(scores, temp, top_idx, top_val, out_pw,
                                     tok_m, tok_i, counts, offsets, cursors);
    k_freq<<<dim3(64, 16), 256, 0, stream>>>(scores, tok_m, tok_i, freq_part);
    k_freq_loss<<<1, 256, 0, stream>>>(freq_part, out_loss);

    // scores now dead: zero x_mlp and pack the mlp weights into the overlay
    k_zero2<<<1024, 256, 0, stream>>>(out, x_mlp);
    k_packw<<<dim3(CTOT, 2, 8), 256, 0, stream>>>(mw1, mw2, W1P, W2P);
    k_scatter<<<NPAIR / 256, 256, 0, stream>>>(top_idx, cursors, lists);
    k_pre_mfma<<<dim3(16, 16), 256, 0, stream>>>(xth, xtl, PPK, pb, pg, pbb,
                                                 counts, offsets, lists, x_h, x_l);
    k_mlp_mfma<<<CTOT * YMLP, 256, 0, stream>>>(x_h, x_l, W1P, W2P, mb1, mb2,
                                                counts, offsets, lists, x_mlp);
    k_post_mfma<<<dim3(16, 16), 256, 0, stream>>>(x_mlp, QPK, qb, qg, qbb, top_val,
                                                  counts, offsets, lists, out);
}

// Round 12
// 493.212 us; speedup vs baseline: 1.3768x; 1.3768x over previous
//
#include <hip/hip_runtime.h>
#include <math.h>

#define DMODEL 256
#define PWAYS  4096
#define TOPK   4
#define HMAX   1280
#define NTOK   2048          // B*S
#define NPAIR  (NTOK*TOPK)   // 8192
#define FSLOTS 16
#define MROWS  64
#define YMLP   8
#define CTOT   56            // total mlp (expert,chunk) pairs: sum over e of 2+e/4

typedef __attribute__((ext_vector_type(8))) short bf16x8;
typedef __attribute__((ext_vector_type(8))) unsigned short u16x8;
typedef __attribute__((ext_vector_type(4))) float f32x4;

#define MFMA_BF16 __builtin_amdgcn_mfma_f32_16x16x32_bf16

__device__ __forceinline__ float gelu_exact(float z) {
    return 0.5f * z * (1.0f + erff(z * 0.70710678118654752440f));
}

__device__ __forceinline__ unsigned short f32_to_bf16_rne(float f) {
    unsigned u = __float_as_uint(f);
    unsigned r = u + 0x7FFFu + ((u >> 16) & 1u);
    return (unsigned short)(r >> 16);
}

__device__ __forceinline__ float bf16_to_f32(unsigned short h) {
    return __uint_as_float((unsigned)h << 16);
}

// chunk_base(e) = sum over e'<e of (2 + e'/4); total = 56
__device__ __forceinline__ int chunk_base(int e) {
    int g = e >> 2, r = e & 3;
    return 4 * (2 * g + (g * (g - 1)) / 2) + r * (2 + g);
}

// ============ front pack (1 launch: cvtx + pack12 + pack3 + packq + zero) ============
// blocks [0,512): x fp32 -> split-bf16
//        [512,536): rw1/rw2 pack
//        [536,792): rw3 pack
//        [792,1048): pw/qw pack
//        [1048]: zero counts/offsets/cursors
__global__ void __launch_bounds__(256) k_pack_front(
    const float* __restrict__ x,
    const float* __restrict__ rw1, const float* __restrict__ rw2,
    const float* __restrict__ rw3,
    const float* __restrict__ pw, const float* __restrict__ qw,
    unsigned short* __restrict__ xth, unsigned short* __restrict__ xtl,
    unsigned short* __restrict__ R1P, unsigned short* __restrict__ R2P,
    unsigned short* __restrict__ P3,
    unsigned short* __restrict__ PPK, unsigned short* __restrict__ QPK,
    int* __restrict__ cnts) {
    const int wg = blockIdx.x;
    const int tid = threadIdx.x;
    const int lane = tid & 63;
    const int l15 = lane & 15, lhi = lane >> 4;

    if (wg < 512) {                       // ---- cvtx ----
        const size_t i = ((size_t)wg * 256 + tid) * 4;
        const float4 v = *(const float4*)&x[i];
        ushort4 hv, lv;
        hv.x = f32_to_bf16_rne(v.x); lv.x = f32_to_bf16_rne(v.x - bf16_to_f32(hv.x));
        hv.y = f32_to_bf16_rne(v.y); lv.y = f32_to_bf16_rne(v.y - bf16_to_f32(hv.y));
        hv.z = f32_to_bf16_rne(v.z); lv.z = f32_to_bf16_rne(v.z - bf16_to_f32(hv.z));
        hv.w = f32_to_bf16_rne(v.w); lv.w = f32_to_bf16_rne(v.w - bf16_to_f32(hv.w));
        *(ushort4*)&xth[i] = hv;
        *(ushort4*)&xtl[i] = lv;
    } else if (wg < 536) {                // ---- pack12 ----
        const int bx = wg - 512;
        const int kq = tid >> 6;
        const bool is1 = (bx < 16);
        const int nb = is1 ? bx : (bx - 16);
        const int N = is1 ? 256 : 128;
        const float* src = is1 ? rw1 : rw2;
        unsigned short* dst = is1 ? R1P : R2P;
        const int nblk = is1 ? 16 : 8;
        const int pstride = nblk * 8 * 512;
        const int n = nb * 16 + l15;
        for (int k2 = 0; k2 < 2; ++k2) {
            const int kb = kq + k2 * 4;
            const int k0 = kb * 32 + lhi * 8;
            u16x8 hv, lv;
#pragma unroll
            for (int j = 0; j < 8; ++j) {
                const float f = src[(size_t)(k0 + j) * N + n];
                const unsigned short h = f32_to_bf16_rne(f);
                hv[j] = h;
                lv[j] = f32_to_bf16_rne(f - bf16_to_f32(h));
            }
            const size_t o = ((size_t)nb * 8 + kb) * 512 + (size_t)lane * 8;
            *(u16x8*)&dst[o] = hv;
            *(u16x8*)&dst[o + pstride] = lv;
        }
    } else if (wg < 792) {                // ---- pack3 ----
        const int nb = wg - 536;
        const int kb = tid >> 6;
        const int k0 = kb * 32 + lhi * 8;
        const int n = nb * 16 + l15;
        u16x8 hv, lv;
#pragma unroll
        for (int j = 0; j < 8; ++j) {
            const float f = rw3[(size_t)(k0 + j) * PWAYS + n];
            const unsigned short h = f32_to_bf16_rne(f);
            hv[j] = h;
            lv[j] = f32_to_bf16_rne(f - bf16_to_f32(h));
        }
        const size_t o0 = ((size_t)(0 * 256 + nb) * 4 + kb) * 512 + (size_t)lane * 8;
        const size_t o1 = ((size_t)(1 * 256 + nb) * 4 + kb) * 512 + (size_t)lane * 8;
        *(u16x8*)&P3[o0] = hv;
        *(u16x8*)&P3[o1] = lv;
    } else if (wg < 1048) {               // ---- packq ----
        const int idx = wg - 792;
        const int e = idx & 15, which = (idx >> 4) & 1, kb = idx >> 5;
        const int wid = tid >> 6;
        const float* src = which ? qw : pw;
        unsigned short* dst = which ? QPK : PPK;
        for (int nb = wid; nb < 16; nb += 4) {
            const int n = nb * 16 + l15;
            const int k0 = kb * 32 + lhi * 8;
            u16x8 hv, lv;
#pragma unroll
            for (int j = 0; j < 8; ++j) {
                const float f = src[(size_t)e * DMODEL * DMODEL + (size_t)(k0 + j) * DMODEL + n];
                const unsigned short h = f32_to_bf16_rne(f);
                hv[j] = h;
                lv[j] = f32_to_bf16_rne(f - bf16_to_f32(h));
            }
            const size_t o0 = ((((size_t)e * 2 + 0) * 16 + nb) * 8 + kb) * 512 + (size_t)lane * 8;
            const size_t o1 = ((((size_t)e * 2 + 1) * 16 + nb) * 8 + kb) * 512 + (size_t)lane * 8;
            *(u16x8*)&dst[o0] = hv;
            *(u16x8*)&dst[o1] = lv;
        }
    } else {                              // ---- wg==1048: zero counts+offsets+cursors ----
        if (tid < 192) cnts[tid] = 0;
    }
}

// ---- mlp weight pack (runs AFTER k_freq: W1P/W2P overlap the scores overlay) ----
__global__ void __launch_bounds__(256) k_packw(
    const float* __restrict__ mw1, const float* __restrict__ mw2,
    unsigned short* __restrict__ W1P, unsigned short* __restrict__ W2P) {
    const int cl = blockIdx.x;          // 0..55
    const int which = blockIdx.y;       // 0: W1, 1: W2
    const int kb = blockIdx.z;          // 0..7
    int e = 0;
    while (e < 15 && chunk_base(e + 1) <= cl) ++e;
    const int ch = cl - chunk_base(e);
    const int hbase = ch * 256;
    const int tid = threadIdx.x;
    const int wid = tid >> 6, lane = tid & 63;
    const int l15 = lane & 15, lhi = lane >> 4;

    unsigned short* dst = which ? W2P : W1P;

    for (int nb = wid; nb < 16; nb += 4) {
        const int n = nb * 16 + l15;
        const int k0 = kb * 32 + lhi * 8;
        u16x8 hv, lv;
#pragma unroll
        for (int j = 0; j < 8; ++j) {
            float f;
            if (which == 0)
                f = mw1[((size_t)e * DMODEL + (k0 + j)) * HMAX + hbase + n];
            else
                f = mw2[((size_t)e * HMAX + hbase + k0 + j) * DMODEL + n];
            const unsigned short h = f32_to_bf16_rne(f);
            hv[j] = h;
            lv[j] = f32_to_bf16_rne(f - bf16_to_f32(h));
        }
        const size_t o0 = ((((size_t)cl * 2 + 0) * 16 + nb) * 8 + kb) * 512 + (size_t)lane * 8;
        const size_t o1 = ((((size_t)cl * 2 + 1) * 16 + nb) * 8 + kb) * 512 + (size_t)lane * 8;
        *(u16x8*)&dst[o0] = hv;
        *(u16x8*)&dst[o1] = lv;
    }
}

// ======================= shared front-end =======================

// zero out[] + x_mlp (both atomic-accumulated)
__global__ void k_zero2(float* __restrict__ out, float* __restrict__ x_mlp) {
    const int i = blockIdx.x * 256 + threadIdx.x;
    const int stride = gridDim.x * 256;
    for (int j = i; j < NTOK * DMODEL; j += stride) out[j] = 0.0f;
    for (int j = i; j < NPAIR * DMODEL; j += stride) x_mlp[j] = 0.0f;
}

// ---- fused router MLP: h1 = gelu(x@rw1+b1); h2 = gelu(h1@rw2+b2) (MFMA) ----
__global__ void __launch_bounds__(256, 2) k_h12(
    const unsigned short* __restrict__ xth, const unsigned short* __restrict__ xtl,
    const unsigned short* __restrict__ R1P, const unsigned short* __restrict__ R2P,
    const float* __restrict__ rb1, const float* __restrict__ rb2,
    unsigned short* __restrict__ h2h, unsigned short* __restrict__ h2l) {
    const int n0 = blockIdx.x * 32;
    const int tid = threadIdx.x;
    const int wid = tid >> 6, lane = tid & 63;
    const int l15 = lane & 15, lhi = lane >> 4;

    __shared__ unsigned short ah[32][264];
    __shared__ unsigned short al[32][264];

    for (int t = tid; t < 1024; t += 256) {
        const int row = t >> 5, seg = (t & 31) * 8;
        const size_t g = (size_t)(n0 + row) * DMODEL + seg;
        *(u16x8*)&ah[row][seg] = *(const u16x8*)&xth[g];
        *(u16x8*)&al[row][seg] = *(const u16x8*)&xtl[g];
    }
    __syncthreads();

    {
        f32x4 acc[2][4];
        const f32x4 zf = {0.f, 0.f, 0.f, 0.f};
#pragma unroll
        for (int ms = 0; ms < 2; ++ms)
#pragma unroll
            for (int ns = 0; ns < 4; ++ns) acc[ms][ns] = zf;

#pragma unroll 1
        for (int kb = 0; kb < 8; ++kb) {
            const int ko = kb * 32 + lhi * 8;
            const bf16x8 a_h0 = *(const bf16x8*)&ah[l15][ko];
            const bf16x8 a_h1 = *(const bf16x8*)&ah[16 + l15][ko];
            const bf16x8 a_l0 = *(const bf16x8*)&al[l15][ko];
            const bf16x8 a_l1 = *(const bf16x8*)&al[16 + l15][ko];
#pragma unroll
            for (int ns = 0; ns < 4; ++ns) {
                const size_t bo = ((size_t)(wid * 4 + ns) * 8 + kb) * 512 + (size_t)lane * 8;
                const bf16x8 bh = *(const bf16x8*)&R1P[bo];
                const bf16x8 bl = *(const bf16x8*)&R1P[bo + 65536];
                acc[0][ns] = MFMA_BF16(a_h0, bh, acc[0][ns], 0, 0, 0);
                acc[1][ns] = MFMA_BF16(a_h1, bh, acc[1][ns], 0, 0, 0);
                acc[0][ns] = MFMA_BF16(a_l0, bh, acc[0][ns], 0, 0, 0);
                acc[1][ns] = MFMA_BF16(a_l1, bh, acc[1][ns], 0, 0, 0);
                acc[0][ns] = MFMA_BF16(a_h0, bl, acc[0][ns], 0, 0, 0);
                acc[1][ns] = MFMA_BF16(a_h1, bl, acc[1][ns], 0, 0, 0);
            }
        }
        __syncthreads();

#pragma unroll
        for (int ms = 0; ms < 2; ++ms)
#pragma unroll
            for (int ns = 0; ns < 4; ++ns) {
                const int col = wid * 64 + ns * 16 + l15;
                const float bias = rb1[col];
#pragma unroll
                for (int r = 0; r < 4; ++r) {
                    const int row = ms * 16 + lhi * 4 + r;
                    const float v = gelu_exact(acc[ms][ns][r] + bias);
                    const unsigned short h = f32_to_bf16_rne(v);
                    ah[row][col] = h;
                    al[row][col] = f32_to_bf16_rne(v - bf16_to_f32(h));
                }
            }
        __syncthreads();
    }

    {
        f32x4 acc2[2][2];
        const f32x4 zf = {0.f, 0.f, 0.f, 0.f};
#pragma unroll
        for (int ms = 0; ms < 2; ++ms)
#pragma unroll
            for (int ns = 0; ns < 2; ++ns) acc2[ms][ns] = zf;

#pragma unroll 1
        for (int kb = 0; kb < 8; ++kb) {
            const int ko = kb * 32 + lhi * 8;
            const bf16x8 a_h0 = *(const bf16x8*)&ah[l15][ko];
            const bf16x8 a_h1 = *(const bf16x8*)&ah[16 + l15][ko];
            const bf16x8 a_l0 = *(const bf16x8*)&al[l15][ko];
            const bf16x8 a_l1 = *(const bf16x8*)&al[16 + l15][ko];
#pragma unroll
            for (int ns = 0; ns < 2; ++ns) {
                const int nb = wid * 2 + ns;
                const size_t bo = ((size_t)nb * 8 + kb) * 512 + (size_t)lane * 8;
                const bf16x8 bh = *(const bf16x8*)&R2P[bo];
                const bf16x8 bl = *(const bf16x8*)&R2P[bo + 32768];
                acc2[0][ns] = MFMA_BF16(a_h0, bh, acc2[0][ns], 0, 0, 0);
                acc2[1][ns] = MFMA_BF16(a_h1, bh, acc2[1][ns], 0, 0, 0);
                acc2[0][ns] = MFMA_BF16(a_l0, bh, acc2[0][ns], 0, 0, 0);
                acc2[1][ns] = MFMA_BF16(a_l1, bh, acc2[1][ns], 0, 0, 0);
                acc2[0][ns] = MFMA_BF16(a_h0, bl, acc2[0][ns], 0, 0, 0);
                acc2[1][ns] = MFMA_BF16(a_h1, bl, acc2[1][ns], 0, 0, 0);
            }
        }

#pragma unroll
        for (int ms = 0; ms < 2; ++ms)
#pragma unroll
            for (int ns = 0; ns < 2; ++ns) {
                const int col = wid * 32 + ns * 16 + l15;
                const float bias = rb2[col];
#pragma unroll
                for (int r = 0; r < 4; ++r) {
                    const int row = ms * 16 + lhi * 4 + r;
                    const float v = gelu_exact(acc2[ms][ns][r] + bias);
                    const unsigned short h = f32_to_bf16_rne(v);
                    const size_t o = (size_t)(n0 + row) * 128 + col;
                    h2h[o] = h;
                    h2l[o] = f32_to_bf16_rne(v - bf16_to_f32(h));
                }
            }
    }
}

// ---- scores GEMM: [2048,128] @ [128,4096] split-bf16 MFMA ----
// 1-D grid, wg&15 = col-tile: all 64 token-tiles of a col-tile share wg%8
// -> one XCD -> its 256KB P3 slice is L2-resident (R6 placement rule).
__global__ void __launch_bounds__(256, 2) k_scores(
    const unsigned short* __restrict__ h2h, const unsigned short* __restrict__ h2l,
    const unsigned short* __restrict__ P3, const float* __restrict__ rb3,
    float* __restrict__ scores) {
    const int wg = blockIdx.x;
    const int by = wg & 15;
    const int n0 = (wg >> 4) * 32;
    const int tid = threadIdx.x;
    const int wid = tid >> 6, lane = tid & 63;
    const int l15 = lane & 15, lhi = lane >> 4;

    __shared__ unsigned short ah[32][136];
    __shared__ unsigned short al[32][136];

    for (int t = tid; t < 512; t += 256) {
        const int row = t >> 4, seg = (t & 15) * 8;
        const size_t g = (size_t)(n0 + row) * 128 + seg;
        *(u16x8*)&ah[row][seg] = *(const u16x8*)&h2h[g];
        *(u16x8*)&al[row][seg] = *(const u16x8*)&h2l[g];
    }
    __syncthreads();

    f32x4 acc[2][4];
    const f32x4 zf = {0.f, 0.f, 0.f, 0.f};
#pragma unroll
    for (int ms = 0; ms < 2; ++ms)
#pragma unroll
        for (int ns = 0; ns < 4; ++ns) acc[ms][ns] = zf;

#pragma unroll 1
    for (int kb = 0; kb < 4; ++kb) {
        const int ko = kb * 32 + lhi * 8;
        const bf16x8 a_h0 = *(const bf16x8*)&ah[l15][ko];
        const bf16x8 a_h1 = *(const bf16x8*)&ah[16 + l15][ko];
        const bf16x8 a_l0 = *(const bf16x8*)&al[l15][ko];
        const bf16x8 a_l1 = *(const bf16x8*)&al[16 + l15][ko];
#pragma unroll
        for (int ns = 0; ns < 4; ++ns) {
            const int nb = by * 16 + wid * 4 + ns;
            const size_t bo = ((size_t)nb * 4 + kb) * 512 + (size_t)lane * 8;
            const bf16x8 bh = *(const bf16x8*)&P3[bo];
            const bf16x8 bl = *(const bf16x8*)&P3[bo + 524288];
            acc[0][ns] = MFMA_BF16(a_h0, bh, acc[0][ns], 0, 0, 0);
            acc[1][ns] = MFMA_BF16(a_h1, bh, acc[1][ns], 0, 0, 0);
            acc[0][ns] = MFMA_BF16(a_l0, bh, acc[0][ns], 0, 0, 0);
            acc[1][ns] = MFMA_BF16(a_l1, bh, acc[1][ns], 0, 0, 0);
            acc[0][ns] = MFMA_BF16(a_h0, bl, acc[0][ns], 0, 0, 0);
            acc[1][ns] = MFMA_BF16(a_h1, bl, acc[1][ns], 0, 0, 0);
        }
    }

#pragma unroll
    for (int ms = 0; ms < 2; ++ms)
#pragma unroll
        for (int ns = 0; ns < 4; ++ns) {
            const int col = by * 256 + wid * 64 + ns * 16 + l15;
            const float bias = rb3[col];
#pragma unroll
            for (int r = 0; r < 4; ++r) {
                const int row = n0 + ms * 16 + lhi * 4 + r;
                scores[(size_t)row * PWAYS + col] = acc[ms][ns][r] + bias;
            }
        }
}

// ---- per-token softmax stats + top-4; writes FULL pw_out row (no pre-zero) ----
// (R8 form: no counts/ticket/prefix — the R11 __threadfence per block caused
//  a 3x serialization; kernel-boundary coherence via k_count/k_prefix is free.)
__global__ void __launch_bounds__(256) k_topk(
    const float* __restrict__ scores, const float* __restrict__ temp,
    int* __restrict__ top_idx, float* __restrict__ top_vals,
    float* __restrict__ pw_out, float* __restrict__ tok_m, float* __restrict__ tok_i) {
    const int n = blockIdx.x;
    const int tid = threadIdx.x;
    const int wid = tid >> 6, lane = tid & 63;
    const float* row = scores + (size_t)n * PWAYS;

    float sv[16];
#pragma unroll
    for (int i = 0; i < 16; ++i) sv[i] = row[tid + i * 256];

    __shared__ float wred[4];
    __shared__ float wr1[4], wrT[4];
    __shared__ float wbv[4];
    __shared__ int wbi[4];
    __shared__ int sel[TOPK];
    __shared__ float selv[TOPK];
    __shared__ float pwv[TOPK];

    float lmax = -3.402823466e38f;
#pragma unroll
    for (int i = 0; i < 16; ++i) lmax = fmaxf(lmax, sv[i]);
    for (int o = 32; o > 0; o >>= 1) lmax = fmaxf(lmax, __shfl_down(lmax, o));
    if (lane == 0) wred[wid] = lmax;
    __syncthreads();
    const float m = fmaxf(fmaxf(wred[0], wred[1]), fmaxf(wred[2], wred[3]));

    const float invT = 1.0f / temp[0];
    float e1 = 0.f, eT = 0.f;
#pragma unroll
    for (int i = 0; i < 16; ++i) {
        const float d = sv[i] - m;
        e1 += expf(d);
        eT += expf(d * invT);
    }
    for (int o = 32; o > 0; o >>= 1) { e1 += __shfl_down(e1, o); eT += __shfl_down(eT, o); }
    if (lane == 0) { wr1[wid] = e1; wrT[wid] = eT; }
    __syncthreads();
    const float sum1 = wr1[0] + wr1[1] + wr1[2] + wr1[3];
    const float sumT = wrT[0] + wrT[1] + wrT[2] + wrT[3];

    for (int r = 0; r < TOPK; ++r) {
        float bv = -3.402823466e38f;
        int bi = PWAYS;
#pragma unroll
        for (int i = 0; i < 16; ++i) {
            const int p = tid + i * 256;
            bool skip = false;
            for (int u = 0; u < r; ++u) if (sel[u] == p) skip = true;
            if (!skip && sv[i] > bv) { bv = sv[i]; bi = p; }
        }
        for (int o = 32; o > 0; o >>= 1) {
            const float ov = __shfl_down(bv, o);
            const int oi = __shfl_down(bi, o);
            if (ov > bv || (ov == bv && oi < bi)) { bv = ov; bi = oi; }
        }
        if (lane == 0) { wbv[wid] = bv; wbi[wid] = bi; }
        __syncthreads();
        if (tid == 0) {
            float b = wbv[0]; int bidx = wbi[0];
            for (int w = 1; w < 4; ++w)
                if (wbv[w] > b || (wbv[w] == b && wbi[w] < bidx)) { b = wbv[w]; bidx = wbi[w]; }
            sel[r] = bidx; selv[r] = b;
        }
        __syncthreads();
    }

    if (tid == 0) {
        float tv[TOPK];
        float wsum = 1e-8f;
#pragma unroll
        for (int k2 = 0; k2 < TOPK; ++k2) {
            tv[k2] = expf((selv[k2] - m) * invT) / sumT;
            wsum += tv[k2];
        }
        const float invw = 1.0f / wsum;
#pragma unroll
        for (int k2 = 0; k2 < TOPK; ++k2) {
            top_idx[n * TOPK + k2] = sel[k2];
            top_vals[n * TOPK + k2] = tv[k2];
            pwv[k2] = tv[k2] * invw;
        }
        tok_m[n] = m;
        tok_i[n] = 1.0f / sum1;
    }
    __syncthreads();

    // full-row write of pathway weights (replaces a 33.5MB zero pass)
#pragma unroll
    for (int i = 0; i < 16; ++i) {
        const int p = tid + i * 256;
        float v = 0.0f;
#pragma unroll
        for (int r = 0; r < TOPK; ++r) if (p == sel[r]) v = pwv[r];
        pw_out[(size_t)n * PWAYS + p] = v;
    }
}

// ---- freq: exclusive-write partial sums of softmax probs (no atomics) ----
__global__ void __launch_bounds__(256) k_freq(
    const float* __restrict__ scores, const float* __restrict__ tok_m,
    const float* __restrict__ tok_i, float* __restrict__ freq_part) {
    const int bx = blockIdx.x;
    const int by = blockIdx.y;
    const int tid = threadIdx.x;
    const int wid = tid >> 6, lane = tid & 63;
    const int col = bx * 64 + lane;

    float acc = 0.f;
    const int r0 = by * 128;
    for (int r = r0 + wid; r < r0 + 128; r += 4) {
        const float mm = tok_m[r], iv = tok_i[r];
        acc += expf(scores[(size_t)r * PWAYS + col] - mm) * iv;
    }
    __shared__ float fs[4][64];
    fs[wid][lane] = acc;
    __syncthreads();
    if (wid == 0)
        freq_part[(size_t)by * PWAYS + col] = fs[0][lane] + fs[1][lane] + fs[2][lane] + fs[3][lane];
}

__global__ void k_freq_loss(const float* __restrict__ freq_part, float* __restrict__ out_loss) {
    __shared__ float fl[PWAYS];
    __shared__ float red[256];
    const int tid = threadIdx.x;
    for (int p = tid; p < PWAYS; p += 256) {
        float s = 0.f;
        for (int sl = 0; sl < FSLOTS; sl++) s += freq_part[(size_t)sl * PWAYS + p];
        fl[p] = s * (1.0f / NTOK);
    }
    __syncthreads();
    float s = 0.f;
    for (int p = tid; p < PWAYS; p += 256) s += fl[p];
    red[tid] = s; __syncthreads();
    for (int st = 128; st > 0; st >>= 1) { if (tid < st) red[tid] += red[tid + st]; __syncthreads(); }
    const float mu = red[0] * (1.0f / PWAYS);
    __syncthreads();
    float ss = 0.f;
    for (int p = tid; p < PWAYS; p += 256) {
        float d = fl[p] - mu;
        ss += d * d;
    }
    red[tid] = ss; __syncthreads();
    for (int st = 128; st > 0; st >>= 1) { if (tid < st) red[tid] += red[tid + st]; __syncthreads(); }
    if (tid == 0)
        out_loss[0] = (float)PWAYS * red[0] / (float)(PWAYS - 1);
}

// ======================= expert-batched back-end =======================

__global__ void k_count(const int* __restrict__ top_idx, int* __restrict__ counts) {
    const int p = blockIdx.x * 256 + threadIdx.x;
    if (p >= NPAIR) return;
    const int idx = top_idx[p];
    atomicAdd(&counts[0 * 16 + (idx >> 8)], 1);
    atomicAdd(&counts[1 * 16 + ((idx >> 4) & 15)], 1);
    atomicAdd(&counts[2 * 16 + (idx & 15)], 1);
}

__global__ void k_prefix(const int* __restrict__ counts, int* __restrict__ offsets,
                         int* __restrict__ cursors) {
    if (threadIdx.x != 0 || blockIdx.x != 0) return;
    for (int s = 0; s < 3; s++) {
        int run = 0;
        for (int e = 0; e < 16; e++) {
            offsets[s * 16 + e] = run;
            cursors[s * 16 + e] = run;
            run += counts[s * 16 + e];
        }
    }
}

__global__ void k_scatter(const int* __restrict__ top_idx, int* __restrict__ cursors,
                          int* __restrict__ lists) {
    const int p = blockIdx.x * 256 + threadIdx.x;
    if (p >= NPAIR) return;
    const int idx = top_idx[p];
    int pos;
    pos = atomicAdd(&cursors[0 * 16 + (idx >> 8)], 1);        lists[0 * NPAIR + pos] = p;
    pos = atomicAdd(&cursors[1 * 16 + ((idx >> 4) & 15)], 1); lists[1 * NPAIR + pos] = p;
    pos = atomicAdd(&cursors[2 * 16 + (idx & 15)], 1);        lists[2 * NPAIR + pos] = p;
}

// ---- stage A: pre experts — MFMA Linear + in-fragment LN + act -> split-bf16 ----
__global__ void __launch_bounds__(256, 2) k_pre_mfma(
    const unsigned short* __restrict__ xth, const unsigned short* __restrict__ xtl,
    const unsigned short* __restrict__ PPK,
    const float* __restrict__ pb, const float* __restrict__ pg, const float* __restrict__ pbb,
    const int* __restrict__ counts, const int* __restrict__ offsets,
    const int* __restrict__ lists,
    unsigned short* __restrict__ x_h, unsigned short* __restrict__ x_l) {
    const int e = blockIdx.x;
    const int cnt = counts[e];
    if (cnt == 0) return;
    const int off = offsets[e];
    const int am = e % 3;
    const int tid = threadIdx.x;
    const int wid = tid >> 6, lane = tid & 63;
    const int l15 = lane & 15, lhi = lane >> 4;

    __shared__ int prs[32];
    __shared__ unsigned short ah[32][264];
    __shared__ unsigned short al[32][264];
    __shared__ float s1s[4][32], s2s[4][32];
    __shared__ float mus[32], ivs[32];

    float bias4[4], g4[4], bb4[4];
#pragma unroll
    for (int ns = 0; ns < 4; ++ns) {
        const int col = wid * 64 + ns * 16 + l15;
        bias4[ns] = pb[e * DMODEL + col];
        g4[ns] = pg[e * DMODEL + col];
        bb4[ns] = pbb[e * DMODEL + col];
    }
    const size_t wbase = (size_t)e * 2 * 65536;

    for (int base = blockIdx.y * 32; base < cnt; base += 16 * 32) {
        const int Tact = min(32, cnt - base);
        if (tid < 32) prs[tid] = lists[off + base + min(tid, Tact - 1)];
        __syncthreads();
        for (int t = tid; t < 1024; t += 256) {
            const int row = t >> 5, seg = (t & 31) * 8;
            const size_t gsrc = (size_t)(prs[row] >> 2) * DMODEL + seg;
            *(uint4*)&ah[row][seg] = *(const uint4*)&xth[gsrc];
            *(uint4*)&al[row][seg] = *(const uint4*)&xtl[gsrc];
        }
        __syncthreads();

        f32x4 acc[2][4];
        const f32x4 zf = {0.f, 0.f, 0.f, 0.f};
#pragma unroll
        for (int ms = 0; ms < 2; ++ms)
#pragma unroll
            for (int ns = 0; ns < 4; ++ns) acc[ms][ns] = zf;

#pragma unroll 1
        for (int kb = 0; kb < 8; ++kb) {
            const int ko = kb * 32 + lhi * 8;
            const bf16x8 a_h0 = *(const bf16x8*)&ah[l15][ko];
            const bf16x8 a_h1 = *(const bf16x8*)&ah[16 + l15][ko];
            const bf16x8 a_l0 = *(const bf16x8*)&al[l15][ko];
            const bf16x8 a_l1 = *(const bf16x8*)&al[16 + l15][ko];
#pragma unroll
            for (int ns = 0; ns < 4; ++ns) {
                const size_t bo = wbase + (size_t)(((wid * 4 + ns) * 8 + kb) * 512 + lane * 8);
                const bf16x8 bh = *(const bf16x8*)&PPK[bo];
                const bf16x8 bl = *(const bf16x8*)&PPK[bo + 65536];
                acc[0][ns] = MFMA_BF16(a_h0, bh, acc[0][ns], 0, 0, 0);
                acc[1][ns] = MFMA_BF16(a_h1, bh, acc[1][ns], 0, 0, 0);
                acc[0][ns] = MFMA_BF16(a_l0, bh, acc[0][ns], 0, 0, 0);
                acc[1][ns] = MFMA_BF16(a_l1, bh, acc[1][ns], 0, 0, 0);
                acc[0][ns] = MFMA_BF16(a_h0, bl, acc[0][ns], 0, 0, 0);
                acc[1][ns] = MFMA_BF16(a_h1, bl, acc[1][ns], 0, 0, 0);
            }
        }

#pragma unroll
        for (int ms = 0; ms < 2; ++ms)
#pragma unroll
            for (int r = 0; r < 4; ++r) {
                float s1 = 0.f, s2 = 0.f;
#pragma unroll
                for (int ns = 0; ns < 4; ++ns) {
                    const float v = acc[ms][ns][r] + bias4[ns];
                    s1 += v; s2 += v * v;
                }
#pragma unroll
                for (int o = 1; o < 16; o <<= 1) {
                    s1 += __shfl_xor(s1, o);
                    s2 += __shfl_xor(s2, o);
                }
                if (l15 == 0) {
                    s1s[wid][ms * 16 + lhi * 4 + r] = s1;
                    s2s[wid][ms * 16 + lhi * 4 + r] = s2;
                }
            }
        __syncthreads();
        if (tid < 32) {
            const float s1 = s1s[0][tid] + s1s[1][tid] + s1s[2][tid] + s1s[3][tid];
            const float s2 = s2s[0][tid] + s2s[1][tid] + s2s[2][tid] + s2s[3][tid];
            const float mu = s1 * (1.0f / DMODEL);
            mus[tid] = mu;
            ivs[tid] = rsqrtf(s2 * (1.0f / DMODEL) - mu * mu + 1e-5f);
        }
        __syncthreads();

#pragma unroll
        for (int ms = 0; ms < 2; ++ms)
#pragma unroll
            for (int ns = 0; ns < 4; ++ns) {
                const int col = wid * 64 + ns * 16 + l15;
#pragma unroll
                for (int r = 0; r < 4; ++r) {
                    const int row = ms * 16 + lhi * 4 + r;
                    if (row < Tact) {
                        const float v = acc[ms][ns][r] + bias4[ns];
                        float y = (v - mus[row]) * ivs[row] * g4[ns] + bb4[ns];
                        y = (am == 0) ? gelu_exact(y) : (am == 1 ? fmaxf(y, 0.f) : tanhf(y));
                        const unsigned short h = f32_to_bf16_rne(y);
                        const size_t o = (size_t)prs[row] * DMODEL + col;
                        x_h[o] = h;
                        x_l[o] = f32_to_bf16_rne(y - bf16_to_f32(h));
                    }
                }
            }
        __syncthreads();
    }
}

// ---- stage B: mlp experts — split-bf16 MFMA, 64-pair x 256-col tiles ----
// 1-D XCD-pinned grid (unchanged; control kernel).
__global__ void __launch_bounds__(256, 2) k_mlp_mfma(
    const unsigned short* __restrict__ x_h, const unsigned short* __restrict__ x_l,
    const unsigned short* __restrict__ W1P, const unsigned short* __restrict__ W2P,
    const float* __restrict__ mb1, const float* __restrict__ mb2,
    const int* __restrict__ counts, const int* __restrict__ offsets,
    const int* __restrict__ lists, float* __restrict__ x_mlp) {
    const int p = blockIdx.x & 7;
    const int j = blockIdx.x >> 3;       // 0..55
    const int ea = p;
    const int eb = (p < 4) ? (p + 12) : (p + 4);
    const int na = (2 + (ea >> 2)) * YMLP;
    int e, ch, y;
    if (j < na) { e = ea; ch = j >> 3; y = j & 7; }
    else        { e = eb; ch = (j - na) >> 3; y = (j - na) & 7; }

    const int cnt = counts[16 + e];
    if (cnt == 0) return;
    const int off = offsets[16 + e];
    const int cl = chunk_base(e) + ch;
    const bool is_gelu = ((e & 1) == 0);
    const int tid = threadIdx.x;
    const int wid = tid >> 6, lane = tid & 63;
    const int l15 = lane & 15, lhi = lane >> 4;

    __shared__ int prs[MROWS];
    __shared__ unsigned short ah[MROWS][264];
    __shared__ unsigned short al[MROWS][264];

    float hb_s[4], ob_s[4];
#pragma unroll
    for (int ns = 0; ns < 4; ++ns) {
        const int col = wid * 64 + ns * 16 + l15;
        hb_s[ns] = mb1[e * HMAX + ch * DMODEL + col];
        ob_s[ns] = (ch == 0) ? mb2[e * DMODEL + col] : 0.0f;
    }

    const size_t wbase = (size_t)cl * 2 * 65536;

    for (int base = y * MROWS; base < cnt; base += YMLP * MROWS) {
        const int Tact = min(MROWS, cnt - base);
        if (tid < MROWS) prs[tid] = lists[NPAIR + off + base + min(tid, Tact - 1)];
        __syncthreads();
        for (int t = tid; t < 2048; t += 256) {
            const int row = t >> 5, seg = (t & 31) * 8;
            const size_t gsrc = (size_t)prs[row] * DMODEL + seg;
            *(uint4*)&ah[row][seg] = *(const uint4*)&x_h[gsrc];
            *(uint4*)&al[row][seg] = *(const uint4*)&x_l[gsrc];
        }
        __syncthreads();

        {
            f32x4 acc[4][4];
            const f32x4 zf = {0.f, 0.f, 0.f, 0.f};
#pragma unroll
            for (int ms = 0; ms < 4; ++ms)
#pragma unroll
                for (int ns = 0; ns < 4; ++ns) acc[ms][ns] = zf;

#pragma unroll 1
            for (int kb = 0; kb < 8; ++kb) {
                const int ko = kb * 32 + lhi * 8;
#pragma unroll
                for (int ns = 0; ns < 4; ++ns) {
                    const size_t bo = wbase + (size_t)(((wid * 4 + ns) * 8 + kb) * 512 + lane * 8);
                    const bf16x8 bh = *(const bf16x8*)&W1P[bo];
                    const bf16x8 bl = *(const bf16x8*)&W1P[bo + 65536];
#pragma unroll
                    for (int ms = 0; ms < 4; ++ms) {
                        const bf16x8 a_h = *(const bf16x8*)&ah[ms * 16 + l15][ko];
                        const bf16x8 a_l = *(const bf16x8*)&al[ms * 16 + l15][ko];
                        acc[ms][ns] = MFMA_BF16(a_h, bh, acc[ms][ns], 0, 0, 0);
                        acc[ms][ns] = MFMA_BF16(a_l, bh, acc[ms][ns], 0, 0, 0);
                        acc[ms][ns] = MFMA_BF16(a_h, bl, acc[ms][ns], 0, 0, 0);
                    }
                }
            }
            __syncthreads();

#pragma unroll
            for (int ms = 0; ms < 4; ++ms)
#pragma unroll
                for (int ns = 0; ns < 4; ++ns) {
                    const int col = wid * 64 + ns * 16 + l15;
#pragma unroll
                    for (int r = 0; r < 4; ++r) {
                        const int row = ms * 16 + lhi * 4 + r;
                        float v = acc[ms][ns][r] + hb_s[ns];
                        v = is_gelu ? gelu_exact(v) : fmaxf(v, 0.0f);
                        const unsigned short h = f32_to_bf16_rne(v);
                        ah[row][col] = h;
                        al[row][col] = f32_to_bf16_rne(v - bf16_to_f32(h));
                    }
                }
            __syncthreads();
        }

        {
            f32x4 acc2[4][4];
            const f32x4 zf = {0.f, 0.f, 0.f, 0.f};
#pragma unroll
            for (int ms = 0; ms < 4; ++ms)
#pragma unroll
                for (int ns = 0; ns < 4; ++ns) acc2[ms][ns] = zf;

#pragma unroll 1
            for (int kb = 0; kb < 8; ++kb) {
                const int ko = kb * 32 + lhi * 8;
#pragma unroll
                for (int ns = 0; ns < 4; ++ns) {
                    const size_t bo = wbase + (size_t)(((wid * 4 + ns) * 8 + kb) * 512 + lane * 8);
                    const bf16x8 bh = *(const bf16x8*)&W2P[bo];
                    const bf16x8 bl = *(const bf16x8*)&W2P[bo + 65536];
#pragma unroll
                    for (int ms = 0; ms < 4; ++ms) {
                        const bf16x8 a_h = *(const bf16x8*)&ah[ms * 16 + l15][ko];
                        const bf16x8 a_l = *(const bf16x8*)&al[ms * 16 + l15][ko];
                        acc2[ms][ns] = MFMA_BF16(a_h, bh, acc2[ms][ns], 0, 0, 0);
                        acc2[ms][ns] = MFMA_BF16(a_l, bh, acc2[ms][ns], 0, 0, 0);
                        acc2[ms][ns] = MFMA_BF16(a_h, bl, acc2[ms][ns], 0, 0, 0);
                    }
                }
            }

#pragma unroll
            for (int ms = 0; ms < 4; ++ms)
#pragma unroll
                for (int ns = 0; ns < 4; ++ns) {
                    const int col = wid * 64 + ns * 16 + l15;
#pragma unroll
                    for (int r = 0; r < 4; ++r) {
                        const int row = ms * 16 + lhi * 4 + r;
                        if (row < Tact)
                            atomicAdd(&x_mlp[(size_t)prs[row] * DMODEL + col],
                                      acc2[ms][ns][r] + ob_s[ns]);
                    }
                }
        }
        __syncthreads();
    }
}

// ---- stage C: post experts — MFMA Linear (+LN if even) + weighted scatter ----
__global__ void __launch_bounds__(256, 2) k_post_mfma(
    const float* __restrict__ x_mlp,
    const unsigned short* __restrict__ QPK,
    const float* __restrict__ qb, const float* __restrict__ qg, const float* __restrict__ qbb,
    const float* __restrict__ top_val,
    const int* __restrict__ counts, const int* __restrict__ offsets,
    const int* __restrict__ lists, float* __restrict__ out) {
    const int e = blockIdx.x;
    const int cnt = counts[32 + e];
    if (cnt == 0) return;
    const int off = offsets[32 + e];
    const bool has_ln = ((e & 1) == 0);
    const int tid = threadIdx.x;
    const int wid = tid >> 6, lane = tid & 63;
    const int l15 = lane & 15, lhi = lane >> 4;

    __shared__ int prs[32];
    __shared__ float tvs[32];
    __shared__ unsigned short ah[32][264];
    __shared__ unsigned short al[32][264];
    __shared__ float s1s[4][32], s2s[4][32];
    __shared__ float mus[32], ivs[32];

    float bias4[4], g4[4], bb4[4];
#pragma unroll
    for (int ns = 0; ns < 4; ++ns) {
        const int col = wid * 64 + ns * 16 + l15;
        bias4[ns] = qb[e * DMODEL + col];
        g4[ns] = qg[e * DMODEL + col];
        bb4[ns] = qbb[e * DMODEL + col];
    }
    const size_t wbase = (size_t)e * 2 * 65536;

    for (int base = blockIdx.y * 32; base < cnt; base += 16 * 32) {
        const int Tact = min(32, cnt - base);
        if (tid < 32) {
            const int p = lists[2 * NPAIR + off + base + min(tid, Tact - 1)];
            prs[tid] = p;
            tvs[tid] = top_val[p];
        }
        __syncthreads();
        for (int t = tid; t < 1024; t += 256) {
            const int row = t >> 5, seg = (t & 31) * 8;
            const float* src = &x_mlp[(size_t)prs[row] * DMODEL + seg];
            const float4 v0 = *(const float4*)&src[0];
            const float4 v1 = *(const float4*)&src[4];
            u16x8 hv, lv;
            const float fv[8] = {v0.x, v0.y, v0.z, v0.w, v1.x, v1.y, v1.z, v1.w};
#pragma unroll
            for (int jj = 0; jj < 8; ++jj) {
                const unsigned short h = f32_to_bf16_rne(fv[jj]);
                hv[jj] = h;
                lv[jj] = f32_to_bf16_rne(fv[jj] - bf16_to_f32(h));
            }
            *(u16x8*)&ah[row][seg] = hv;
            *(u16x8*)&al[row][seg] = lv;
        }
        __syncthreads();

        f32x4 acc[2][4];
        const f32x4 zf = {0.f, 0.f, 0.f, 0.f};
#pragma unroll
        for (int ms = 0; ms < 2; ++ms)
#pragma unroll
            for (int ns = 0; ns < 4; ++ns) acc[ms][ns] = zf;

#pragma unroll 1
        for (int kb = 0; kb < 8; ++kb) {
            const int ko = kb * 32 + lhi * 8;
            const bf16x8 a_h0 = *(const bf16x8*)&ah[l15][ko];
            const bf16x8 a_h1 = *(const bf16x8*)&ah[16 + l15][ko];
            const bf16x8 a_l0 = *(const bf16x8*)&al[l15][ko];
            const bf16x8 a_l1 = *(const bf16x8*)&al[16 + l15][ko];
#pragma unroll
            for (int ns = 0; ns < 4; ++ns) {
                const size_t bo = wbase + (size_t)(((wid * 4 + ns) * 8 + kb) * 512 + lane * 8);
                const bf16x8 bh = *(const bf16x8*)&QPK[bo];
                const bf16x8 bl = *(const bf16x8*)&QPK[bo + 65536];
                acc[0][ns] = MFMA_BF16(a_h0, bh, acc[0][ns], 0, 0, 0);
                acc[1][ns] = MFMA_BF16(a_h1, bh, acc[1][ns], 0, 0, 0);
                acc[0][ns] = MFMA_BF16(a_l0, bh, acc[0][ns], 0, 0, 0);
                acc[1][ns] = MFMA_BF16(a_l1, bh, acc[1][ns], 0, 0, 0);
                acc[0][ns] = MFMA_BF16(a_h0, bl, acc[0][ns], 0, 0, 0);
                acc[1][ns] = MFMA_BF16(a_h1, bl, acc[1][ns], 0, 0, 0);
            }
        }

        if (has_ln) {
#pragma unroll
            for (int ms = 0; ms < 2; ++ms)
#pragma unroll
                for (int r = 0; r < 4; ++r) {
                    float s1 = 0.f, s2 = 0.f;
#pragma unroll
                    for (int ns = 0; ns < 4; ++ns) {
                        const float v = acc[ms][ns][r] + bias4[ns];
                        s1 += v; s2 += v * v;
                    }
#pragma unroll
                    for (int o = 1; o < 16; o <<= 1) {
                        s1 += __shfl_xor(s1, o);
                        s2 += __shfl_xor(s2, o);
                    }
                    if (l15 == 0) {
                        s1s[wid][ms * 16 + lhi * 4 + r] = s1;
                        s2s[wid][ms * 16 + lhi * 4 + r] = s2;
                    }
                }
            __syncthreads();
            if (tid < 32) {
                const float s1 = s1s[0][tid] + s1s[1][tid] + s1s[2][tid] + s1s[3][tid];
                const float s2 = s2s[0][tid] + s2s[1][tid] + s2s[2][tid] + s2s[3][tid];
                const float mu = s1 * (1.0f / DMODEL);
                mus[tid] = mu;
                ivs[tid] = rsqrtf(s2 * (1.0f / DMODEL) - mu * mu + 1e-5f);
            }
            __syncthreads();
        }

#pragma unroll
        for (int ms = 0; ms < 2; ++ms)
#pragma unroll
            for (int ns = 0; ns < 4; ++ns) {
                const int col = wid * 64 + ns * 16 + l15;
#pragma unroll
                for (int r = 0; r < 4; ++r) {
                    const int row = ms * 16 + lhi * 4 + r;
                    if (row < Tact) {
                        const float v = acc[ms][ns][r] + bias4[ns];
                        const float t = has_ln ? ((v - mus[row]) * ivs[row] * g4[ns] + bb4[ns]) : v;
                        atomicAdd(&out[(size_t)(prs[row] >> 2) * DMODEL + col], tvs[row] * t);
                    }
                }
            }
        __syncthreads();
    }
}

// ---------------------------------------------------------------------------
extern "C" void kernel_launch(void* const* d_in, const int* in_sizes, int n_in,
                              void* d_out, int out_size, void* d_ws, size_t ws_size,
                              hipStream_t stream) {
    (void)in_sizes; (void)n_in; (void)out_size; (void)ws_size;

    const float* x    = (const float*)d_in[0];
    const float* rw1  = (const float*)d_in[1];
    const float* rb1  = (const float*)d_in[2];
    const float* rw2  = (const float*)d_in[3];
    const float* rb2  = (const float*)d_in[4];
    const float* rw3  = (const float*)d_in[5];
    const float* rb3  = (const float*)d_in[6];
    const float* temp = (const float*)d_in[7];
    const float* pw   = (const float*)d_in[8];
    const float* pb   = (const float*)d_in[9];
    const float* pg   = (const float*)d_in[10];
    const float* pbb  = (const float*)d_in[11];
    const float* mw1  = (const float*)d_in[12];
    const float* mb1  = (const float*)d_in[13];
    const float* mw2  = (const float*)d_in[14];
    const float* mb2  = (const float*)d_in[15];
    const float* qw   = (const float*)d_in[16];
    const float* qb   = (const float*)d_in[17];
    const float* qg   = (const float*)d_in[18];
    const float* qbb  = (const float*)d_in[19];

    float* out      = (float*)d_out;
    float* out_loss = out + (size_t)NTOK * DMODEL;
    float* out_pw   = out_loss + 1;

    float* freq_part = (float*)d_ws;                                  // 65536 f
    int*   top_idx   = (int*)(freq_part + (size_t)FSLOTS * PWAYS);    // 8192 i
    float* top_val   = (float*)(top_idx + NPAIR);                     // 8192 f
    int*   counts    = (int*)(top_val + NPAIR);                       // 64 i
    int*   offsets   = counts + 64;                                   // 64 i
    int*   cursors   = offsets + 64;                                  // 64 i
    int*   lists     = cursors + 64;                                  // 3*8192 i
    float* x_mlp     = (float*)(lists + 3 * NPAIR);                   // 8192*256 f
    unsigned short* x_h = (unsigned short*)(x_mlp + (size_t)NPAIR * DMODEL); // 8192*256 bf16
    unsigned short* x_l = x_h + (size_t)NPAIR * DMODEL;                      // 8192*256 bf16
    unsigned short* W1P = x_l + (size_t)NPAIR * DMODEL;               // 56*2*65536 bf16
    unsigned short* W2P = W1P + (size_t)CTOT * 2 * 65536;             // 56*2*65536 bf16
    unsigned short* P3  = W2P + (size_t)CTOT * 2 * 65536;             // 2*524288 bf16
    unsigned short* h2h = P3 + 2 * 524288;                            // 2048*128 bf16
    unsigned short* h2l = h2h + (size_t)NTOK * 128;                   // 2048*128 bf16
    float* tok_m = (float*)(h2l + (size_t)NTOK * 128);                // 2048 f
    float* tok_i = tok_m + NTOK;                                      // 2048 f
    unsigned short* xth = (unsigned short*)(tok_i + NTOK);            // 2048*256 bf16
    unsigned short* xtl = xth + (size_t)NTOK * DMODEL;                // 2048*256 bf16
    unsigned short* PPK = xtl + (size_t)NTOK * DMODEL;                // 16*2*65536 bf16
    unsigned short* QPK = PPK + (size_t)16 * 2 * 65536;               // 16*2*65536 bf16
    unsigned short* R1P = QPK + (size_t)16 * 2 * 65536;               // 2*65536 bf16
    unsigned short* R2P = R1P + 2 * 65536;                            // 2*32768 bf16
    // scores [2048][4096] f32 (33.5MB) overlays x_mlp..W2P. W1P/W2P overlap
    // the overlay, so the mlp weights are packed by k_packw AFTER k_freq
    // (when scores is dead). P3/PPK/QPK/R1P/R2P live outside the overlay.
    float* scores = x_mlp;

    // front pack: cvtx(512) + pack12(24) + pack3(256) + packq(256) + zero(1)
    k_pack_front<<<1049, 256, 0, stream>>>(x, rw1, rw2, rw3, pw, qw,
                                           xth, xtl, R1P, R2P, P3, PPK, QPK,
                                           counts);
    k_h12<<<NTOK / 32, 256, 0, stream>>>(xth, xtl, R1P, R2P, rb1, rb2, h2h, h2l);
    k_scores<<<1024, 256, 0, stream>>>(h2h, h2l, P3, rb3, scores);
    k_topk<<<NTOK, 256, 0, stream>>>(scores, temp, top_idx, top_val, out_pw,
                                     tok_m, tok_i);
    k_freq<<<dim3(64, 16), 256, 0, stream>>>(scores, tok_m, tok_i, freq_part);
    k_freq_loss<<<1, 256, 0, stream>>>(freq_part, out_loss);

    // scores now dead: zero x_mlp and pack the mlp weights into the overlay
    k_zero2<<<1024, 256, 0, stream>>>(out, x_mlp);
    k_packw<<<dim3(CTOT, 2, 8), 256, 0, stream>>>(mw1, mw2, W1P, W2P);
    k_count<<<NPAIR / 256, 256, 0, stream>>>(top_idx, counts);
    k_prefix<<<1, 64, 0, stream>>>(counts, offsets, cursors);
    k_scatter<<<NPAIR / 256, 256, 0, stream>>>(top_idx, cursors, lists);
    k_pre_mfma<<<dim3(16, 16), 256, 0, stream>>>(xth, xtl, PPK, pb, pg, pbb,
                                                 counts, offsets, lists, x_h, x_l);
    k_mlp_mfma<<<CTOT * YMLP, 256, 0, stream>>>(x_h, x_l, W1P, W2P, mb1, mb2,
                                                counts, offsets, lists, x_mlp);
    k_post_mfma<<<dim3(16, 16), 256, 0, stream>>>(x_mlp, QPK, qb, qg, qbb, top_val,
                                                  counts, offsets, lists, out);
}